// Round 1
// baseline (628.176 us; speedup 1.0000x reference)
//
#include <hip/hip_runtime.h>
#include <hip/hip_bf16.h>
#include <stdint.h>

// CausalSelfAttention: B=4 S=2048 D=1024 H=16 hd=64
// Pipeline: conv(x,wT) -> QKV gemm (bf16 mfma, epilogue scatters Q,K,V^T)
//           -> flash attention (online softmax, base-2, scale folded into Q)
//           -> out-proj gemm (f32 out + bias)

#define B_   4
#define S_   2048
#define D_   1024
#define H_   16
#define HD_  64
#define MTOK (B_ * S_)   // 8192

typedef __attribute__((ext_vector_type(8))) short bfx8;
typedef __attribute__((ext_vector_type(4))) float fx4;

static __device__ __forceinline__ unsigned short f2bf(float f) {
    union { float f; uint32_t u; } v{f};
    uint32_t u = v.u;
    u += 0x7fffu + ((u >> 16) & 1u);   // RNE
    return (unsigned short)(u >> 16);
}

// ---------------- convert x f32 -> bf16 ----------------
__global__ void k_conv_x(const float* __restrict__ x, unsigned short* __restrict__ xb, int n8) {
    int i = blockIdx.x * blockDim.x + threadIdx.x;
    int stride = gridDim.x * blockDim.x;
    for (; i < n8; i += stride) {
        const float4* p = (const float4*)(x + (size_t)i * 8);
        float4 a = p[0], b = p[1];
        bfx8 o;
        o[0]=f2bf(a.x); o[1]=f2bf(a.y); o[2]=f2bf(a.z); o[3]=f2bf(a.w);
        o[4]=f2bf(b.x); o[5]=f2bf(b.y); o[6]=f2bf(b.z); o[7]=f2bf(b.w);
        *(bfx8*)(xb + (size_t)i * 8) = o;
    }
}

// ---------------- transpose W [K][N] f32 -> Wt [N][K] bf16 ----------------
__global__ void k_transpose_bf(const float* __restrict__ w, unsigned short* __restrict__ wt,
                               int K, int N) {
    int idx = blockIdx.x * blockDim.x + threadIdx.x;
    int total = N * (K / 8);
    if (idx >= total) return;
    int n  = idx % N;        // consecutive threads -> consecutive n -> coalesced reads
    int k0 = (idx / N) * 8;
    bfx8 o;
#pragma unroll
    for (int j = 0; j < 8; ++j) o[j] = f2bf(w[(size_t)(k0 + j) * N + n]);
    *(bfx8*)(wt + (size_t)n * K + k0) = o;
}

// ---------------- QKV GEMM: [8192,1024] x [1024,3072] ----------------
// A row-major [M][K] bf16, Bt row-major [N][K] bf16. 128x128 tile, BK=32, 4 waves.
#define BK 32
#define QSCALE 0.18033688011112042f   // 0.125 * log2(e)

__launch_bounds__(256)
__global__ void k_gemm_qkv(const unsigned short* __restrict__ A,
                           const unsigned short* __restrict__ Bt,
                           const float* __restrict__ bias,
                           unsigned short* __restrict__ Qw,
                           unsigned short* __restrict__ Kw,
                           unsigned short* __restrict__ Vt) {
    __shared__ unsigned short Al[128 * BK];
    __shared__ unsigned short Bl[128 * BK];
    const int m0 = blockIdx.y * 128;
    const int n0 = blockIdx.x * 128;
    const int t = threadIdx.x;
    const int w = t >> 6, l = t & 63;
    const int wr = w >> 1, wc = w & 1;
    const int lr = l & 15, lg = l >> 4;
    fx4 acc[4][4] = {};

    for (int k0 = 0; k0 < D_; k0 += BK) {
        __syncthreads();
#pragma unroll
        for (int j = 0; j < 2; ++j) {
            int id = t + 256 * j;           // 512 chunks of 16B
            int row = id >> 2, q = id & 3;
            *(bfx8*)&Al[row * BK + q * 8] = *(const bfx8*)&A [(size_t)(m0 + row) * D_ + k0 + q * 8];
            *(bfx8*)&Bl[row * BK + q * 8] = *(const bfx8*)&Bt[(size_t)(n0 + row) * D_ + k0 + q * 8];
        }
        __syncthreads();
        bfx8 af[4], bf[4];
#pragma unroll
        for (int i = 0; i < 4; ++i) af[i] = *(const bfx8*)&Al[(wr * 64 + i * 16 + lr) * BK + lg * 8];
#pragma unroll
        for (int i = 0; i < 4; ++i) bf[i] = *(const bfx8*)&Bl[(wc * 64 + i * 16 + lr) * BK + lg * 8];
#pragma unroll
        for (int mi = 0; mi < 4; ++mi)
#pragma unroll
            for (int ni = 0; ni < 4; ++ni)
                acc[mi][ni] = __builtin_amdgcn_mfma_f32_16x16x32_bf16(af[mi], bf[ni], acc[mi][ni], 0, 0, 0);
    }

    // epilogue: scatter to Q [bh][s][64] (scaled), K [bh][s][64], V^T [bh][64][s]
    const int colbase = n0 + wc * 64;
    const int mat = colbase >> 10;          // uniform across block (128 | 1024)
#pragma unroll
    for (int ni = 0; ni < 4; ++ni) {
        int col = colbase + ni * 16 + lr;
        int dcol = col & 1023;
        int h = dcol >> 6, dd = dcol & 63;
        float bv = bias[col];
#pragma unroll
        for (int mi = 0; mi < 4; ++mi) {
#pragma unroll
            for (int i = 0; i < 4; ++i) {
                int m = m0 + wr * 64 + mi * 16 + lg * 4 + i;
                int b = m >> 11, s = m & 2047;
                float v = acc[mi][ni][i] + bv;
                int bh = b * H_ + h;
                if (mat == 0)      Qw[((size_t)bh * S_ + s) * HD_ + dd] = f2bf(v * QSCALE);
                else if (mat == 1) Kw[((size_t)bh * S_ + s) * HD_ + dd] = f2bf(v);
                else               Vt[((size_t)bh * HD_ + dd) * S_ + s] = f2bf(v);
            }
        }
    }
}

// ---------------- flash attention ----------------
// block: 4 waves, each wave owns 16 q-rows; q-tile 64; kv-tile 64; no inter-wave sync.
__launch_bounds__(256)
__global__ void k_attn(const unsigned short* __restrict__ Qw,
                       const unsigned short* __restrict__ Kw,
                       const unsigned short* __restrict__ Vt,
                       unsigned short* __restrict__ Ob) {
    __shared__ unsigned short Pl[4][16 * 72];   // per-wave P tile, padded row stride 72 (=9x16B)
    const int bh = blockIdx.y;
    const int q0 = blockIdx.x * 64;
    const int t = threadIdx.x;
    const int w = t >> 6, l = t & 63;
    const int lr = l & 15, lg = l >> 4;
    const int q0w = q0 + w * 16;

    const unsigned short* Qp = Qw + (size_t)bh * S_ * HD_;
    const unsigned short* Kp = Kw + (size_t)bh * S_ * HD_;
    const unsigned short* Vp = Vt + (size_t)bh * HD_ * S_;

    bfx8 qf[2];
#pragma unroll
    for (int kk = 0; kk < 2; ++kk)
        qf[kk] = *(const bfx8*)&Qp[(size_t)(q0w + lr) * HD_ + kk * 32 + lg * 8];

    fx4 oacc[4] = {};
    float mrow[4], lsum[4];
#pragma unroll
    for (int i = 0; i < 4; ++i) { mrow[i] = -1e30f; lsum[i] = 0.f; }

    const int nt = (q0w + 15) / 64 + 1;
    for (int tkv = 0; tkv < nt; ++tkv) {
        const int kv0 = tkv * 64;
        // --- S = Q K^T (scale pre-folded into Q, base-2 domain) ---
        fx4 sacc[4] = {};
#pragma unroll
        for (int c = 0; c < 4; ++c)
#pragma unroll
            for (int kk = 0; kk < 2; ++kk) {
                bfx8 kf = *(const bfx8*)&Kp[(size_t)(kv0 + c * 16 + lr) * HD_ + kk * 32 + lg * 8];
                sacc[c] = __builtin_amdgcn_mfma_f32_16x16x32_bf16(qf[kk], kf, sacc[c], 0, 0, 0);
            }
        // --- causal mask: only the final tile straddles the diagonal ---
        if (tkv == nt - 1) {
#pragma unroll
            for (int c = 0; c < 4; ++c)
#pragma unroll
                for (int i = 0; i < 4; ++i)
                    if (kv0 + c * 16 + lr > q0w + lg * 4 + i) sacc[c][i] = -1e30f;
        }
        // --- row max (16-lane group reduce; rows are lane-groups x reg) ---
        float pmax[4], alpha[4];
#pragma unroll
        for (int i = 0; i < 4; ++i) {
            float mx = fmaxf(fmaxf(sacc[0][i], sacc[1][i]), fmaxf(sacc[2][i], sacc[3][i]));
            mx = fmaxf(mx, __shfl_xor(mx, 1));
            mx = fmaxf(mx, __shfl_xor(mx, 2));
            mx = fmaxf(mx, __shfl_xor(mx, 4));
            mx = fmaxf(mx, __shfl_xor(mx, 8));
            float mnew = fmaxf(mrow[i], mx);
            alpha[i] = exp2f(mrow[i] - mnew);
            mrow[i] = mnew;
            pmax[i] = mx;
        }
        // --- P = exp2(S-m), accumulate row sums, stash P in LDS as bf16 ---
        float psum[4] = {0.f, 0.f, 0.f, 0.f};
#pragma unroll
        for (int c = 0; c < 4; ++c)
#pragma unroll
            for (int i = 0; i < 4; ++i) {
                float p = exp2f(sacc[c][i] - mrow[i]);
                psum[i] += p;
                Pl[w][(lg * 4 + i) * 72 + c * 16 + lr] = f2bf(p);
            }
#pragma unroll
        for (int i = 0; i < 4; ++i) {
            float s = psum[i];
            s += __shfl_xor(s, 1);
            s += __shfl_xor(s, 2);
            s += __shfl_xor(s, 4);
            s += __shfl_xor(s, 8);
            lsum[i] = lsum[i] * alpha[i] + s;
        }
#pragma unroll
        for (int c = 0; c < 4; ++c)
#pragma unroll
            for (int i = 0; i < 4; ++i) oacc[c][i] *= alpha[i];
        // --- O += P V  (A-frag of P from LDS; V^T rows are contiguous in kv) ---
#pragma unroll
        for (int kk = 0; kk < 2; ++kk) {
            bfx8 pf = *(const bfx8*)&Pl[w][lr * 72 + kk * 32 + lg * 8];
#pragma unroll
            for (int c = 0; c < 4; ++c) {
                bfx8 vf = *(const bfx8*)&Vp[(size_t)(c * 16 + lr) * S_ + kv0 + kk * 32 + lg * 8];
                oacc[c] = __builtin_amdgcn_mfma_f32_16x16x32_bf16(pf, vf, oacc[c], 0, 0, 0);
            }
        }
    }
    // --- write attn output bf16 [b][s][h*64+d] ---
    const int b = bh >> 4, h = bh & 15;
#pragma unroll
    for (int c = 0; c < 4; ++c)
#pragma unroll
        for (int i = 0; i < 4; ++i) {
            int srow = q0w + lg * 4 + i;
            int col = h * 64 + c * 16 + lr;
            Ob[((size_t)b * S_ + srow) * D_ + col] = f2bf(oacc[c][i] / lsum[i]);
        }
}

// ---------------- out-proj GEMM: [8192,1024] x [1024,1024] + bias, f32 out ----------------
__launch_bounds__(256)
__global__ void k_gemm_proj(const unsigned short* __restrict__ A,
                            const unsigned short* __restrict__ Bt,
                            const float* __restrict__ bias,
                            float* __restrict__ out) {
    __shared__ unsigned short Al[128 * BK];
    __shared__ unsigned short Bl[128 * BK];
    const int m0 = blockIdx.y * 128;
    const int n0 = blockIdx.x * 128;
    const int t = threadIdx.x;
    const int w = t >> 6, l = t & 63;
    const int wr = w >> 1, wc = w & 1;
    const int lr = l & 15, lg = l >> 4;
    fx4 acc[4][4] = {};

    for (int k0 = 0; k0 < D_; k0 += BK) {
        __syncthreads();
#pragma unroll
        for (int j = 0; j < 2; ++j) {
            int id = t + 256 * j;
            int row = id >> 2, q = id & 3;
            *(bfx8*)&Al[row * BK + q * 8] = *(const bfx8*)&A [(size_t)(m0 + row) * D_ + k0 + q * 8];
            *(bfx8*)&Bl[row * BK + q * 8] = *(const bfx8*)&Bt[(size_t)(n0 + row) * D_ + k0 + q * 8];
        }
        __syncthreads();
        bfx8 af[4], bf[4];
#pragma unroll
        for (int i = 0; i < 4; ++i) af[i] = *(const bfx8*)&Al[(wr * 64 + i * 16 + lr) * BK + lg * 8];
#pragma unroll
        for (int i = 0; i < 4; ++i) bf[i] = *(const bfx8*)&Bl[(wc * 64 + i * 16 + lr) * BK + lg * 8];
#pragma unroll
        for (int mi = 0; mi < 4; ++mi)
#pragma unroll
            for (int ni = 0; ni < 4; ++ni)
                acc[mi][ni] = __builtin_amdgcn_mfma_f32_16x16x32_bf16(af[mi], bf[ni], acc[mi][ni], 0, 0, 0);
    }
#pragma unroll
    for (int ni = 0; ni < 4; ++ni) {
        int col = n0 + wc * 64 + ni * 16 + lr;
        float bv = bias[col];
#pragma unroll
        for (int mi = 0; mi < 4; ++mi)
#pragma unroll
            for (int i = 0; i < 4; ++i) {
                int m = m0 + wr * 64 + mi * 16 + lg * 4 + i;
                out[(size_t)m * D_ + col] = acc[mi][ni][i] + bv;
            }
    }
}

extern "C" void kernel_launch(void* const* d_in, const int* in_sizes, int n_in,
                              void* d_out, int out_size, void* d_ws, size_t ws_size,
                              hipStream_t stream) {
    const float* x     = (const float*)d_in[0];
    const float* w_qkv = (const float*)d_in[1];
    const float* b_qkv = (const float*)d_in[2];
    const float* w_out = (const float*)d_in[3];
    const float* b_out = (const float*)d_in[4];
    float* out = (float*)d_out;

    // workspace layout (bf16 elements)
    unsigned short* xb    = (unsigned short*)d_ws;          // 8192*1024
    unsigned short* wqkvT = xb    + (size_t)MTOK * D_;      // 3072*1024
    unsigned short* woutT = wqkvT + (size_t)3 * D_ * D_;    // 1024*1024
    unsigned short* Qw    = woutT + (size_t)D_ * D_;        // 8192*1024
    unsigned short* Kw    = Qw    + (size_t)MTOK * D_;
    unsigned short* Vt    = Kw    + (size_t)MTOK * D_;
    unsigned short* attnb = Vt    + (size_t)MTOK * D_;

    k_conv_x<<<2048, 256, 0, stream>>>(x, xb, MTOK * D_ / 8);
    k_transpose_bf<<<(3 * D_ * (D_ / 8)) / 256, 256, 0, stream>>>(w_qkv, wqkvT, D_, 3 * D_);
    k_transpose_bf<<<(D_ * (D_ / 8)) / 256, 256, 0, stream>>>(w_out, woutT, D_, D_);
    k_gemm_qkv<<<dim3(24, 64), 256, 0, stream>>>(xb, wqkvT, b_qkv, Qw, Kw, Vt);
    k_attn<<<dim3(S_ / 64, B_ * H_), 256, 0, stream>>>(Qw, Kw, Vt, attnb);
    k_gemm_proj<<<dim3(8, 64), 256, 0, stream>>>(attnb, woutT, b_out, out);
}

// Round 2
// 413.595 us; speedup vs baseline: 1.5188x; 1.5188x over previous
//
#include <hip/hip_runtime.h>
#include <hip/hip_bf16.h>
#include <stdint.h>

// CausalSelfAttention: B=4 S=2048 D=1024 H=16 hd=64
// Pipeline: conv(x,wT) -> QKV gemm (bf16 mfma, epilogue scatters Q,K,V^T)
//           -> flash attention (LDS-staged K/V, online softmax, base-2)
//           -> out-proj gemm (f32 out + bias)

#define B_   4
#define S_   2048
#define D_   1024
#define H_   16
#define HD_  64
#define MTOK (B_ * S_)   // 8192

typedef __attribute__((ext_vector_type(8))) short bfx8;
typedef __attribute__((ext_vector_type(4))) float fx4;

static __device__ __forceinline__ unsigned short f2bf(float f) {
    union { float f; uint32_t u; } v{f};
    uint32_t u = v.u;
    u += 0x7fffu + ((u >> 16) & 1u);   // RNE
    return (unsigned short)(u >> 16);
}

// ---------------- convert x f32 -> bf16 ----------------
__global__ void k_conv_x(const float* __restrict__ x, unsigned short* __restrict__ xb, int n8) {
    int i = blockIdx.x * blockDim.x + threadIdx.x;
    int stride = gridDim.x * blockDim.x;
    for (; i < n8; i += stride) {
        const float4* p = (const float4*)(x + (size_t)i * 8);
        float4 a = p[0], b = p[1];
        bfx8 o;
        o[0]=f2bf(a.x); o[1]=f2bf(a.y); o[2]=f2bf(a.z); o[3]=f2bf(a.w);
        o[4]=f2bf(b.x); o[5]=f2bf(b.y); o[6]=f2bf(b.z); o[7]=f2bf(b.w);
        *(bfx8*)(xb + (size_t)i * 8) = o;
    }
}

// ---------------- transpose W [K][N] f32 -> Wt [N][K] bf16 ----------------
__global__ void k_transpose_bf(const float* __restrict__ w, unsigned short* __restrict__ wt,
                               int K, int N) {
    int idx = blockIdx.x * blockDim.x + threadIdx.x;
    int total = N * (K / 8);
    if (idx >= total) return;
    int n  = idx % N;        // consecutive threads -> consecutive n -> coalesced reads
    int k0 = (idx / N) * 8;
    bfx8 o;
#pragma unroll
    for (int j = 0; j < 8; ++j) o[j] = f2bf(w[(size_t)(k0 + j) * N + n]);
    *(bfx8*)(wt + (size_t)n * K + k0) = o;
}

// ---------------- QKV GEMM: [8192,1024] x [1024,3072] ----------------
#define BK 32
#define QSCALE 0.18033688011112042f   // 0.125 * log2(e)

__launch_bounds__(256)
__global__ void k_gemm_qkv(const unsigned short* __restrict__ A,
                           const unsigned short* __restrict__ Bt,
                           const float* __restrict__ bias,
                           unsigned short* __restrict__ Qw,
                           unsigned short* __restrict__ Kw,
                           unsigned short* __restrict__ Vt) {
    __shared__ unsigned short Al[128 * BK];
    __shared__ unsigned short Bl[128 * BK];
    const int m0 = blockIdx.y * 128;
    const int n0 = blockIdx.x * 128;
    const int t = threadIdx.x;
    const int w = t >> 6, l = t & 63;
    const int wr = w >> 1, wc = w & 1;
    const int lr = l & 15, lg = l >> 4;
    fx4 acc[4][4] = {};

    for (int k0 = 0; k0 < D_; k0 += BK) {
        __syncthreads();
#pragma unroll
        for (int j = 0; j < 2; ++j) {
            int id = t + 256 * j;           // 512 chunks of 16B
            int row = id >> 2, q = id & 3;
            *(bfx8*)&Al[row * BK + q * 8] = *(const bfx8*)&A [(size_t)(m0 + row) * D_ + k0 + q * 8];
            *(bfx8*)&Bl[row * BK + q * 8] = *(const bfx8*)&Bt[(size_t)(n0 + row) * D_ + k0 + q * 8];
        }
        __syncthreads();
        bfx8 af[4], bf[4];
#pragma unroll
        for (int i = 0; i < 4; ++i) af[i] = *(const bfx8*)&Al[(wr * 64 + i * 16 + lr) * BK + lg * 8];
#pragma unroll
        for (int i = 0; i < 4; ++i) bf[i] = *(const bfx8*)&Bl[(wc * 64 + i * 16 + lr) * BK + lg * 8];
#pragma unroll
        for (int mi = 0; mi < 4; ++mi)
#pragma unroll
            for (int ni = 0; ni < 4; ++ni)
                acc[mi][ni] = __builtin_amdgcn_mfma_f32_16x16x32_bf16(af[mi], bf[ni], acc[mi][ni], 0, 0, 0);
    }

    const int colbase = n0 + wc * 64;
    const int mat = colbase >> 10;
#pragma unroll
    for (int ni = 0; ni < 4; ++ni) {
        int col = colbase + ni * 16 + lr;
        int dcol = col & 1023;
        int h = dcol >> 6, dd = dcol & 63;
        float bv = bias[col];
#pragma unroll
        for (int mi = 0; mi < 4; ++mi) {
#pragma unroll
            for (int i = 0; i < 4; ++i) {
                int m = m0 + wr * 64 + mi * 16 + lg * 4 + i;
                int b = m >> 11, s = m & 2047;
                float v = acc[mi][ni][i] + bv;
                int bh = b * H_ + h;
                if (mat == 0)      Qw[((size_t)bh * S_ + s) * HD_ + dd] = f2bf(v * QSCALE);
                else if (mat == 1) Kw[((size_t)bh * S_ + s) * HD_ + dd] = f2bf(v);
                else               Vt[((size_t)bh * HD_ + dd) * S_ + s] = f2bf(v);
            }
        }
    }
}

// ---------------- flash attention ----------------
// 4 waves/block, 32 q-rows/wave (q-block 128), kv-tile 64.
// K and V^T tiles staged in LDS (XOR-swizzled), double-buffered, shared by all waves.
__launch_bounds__(256)
__global__ void k_attn(const unsigned short* __restrict__ Qw,
                       const unsigned short* __restrict__ Kw,
                       const unsigned short* __restrict__ Vt,
                       unsigned short* __restrict__ Ob) {
    __shared__ unsigned short Kl[2][64 * 64];   // [kv][d], row=128B, swizzled
    __shared__ unsigned short Vl[2][64 * 64];   // [d][kv], row=128B, swizzled
    __shared__ unsigned short Pl[4][32 * 72];   // per-wave P, padded stride 72
    const int bh = blockIdx.y;
    const int q0 = blockIdx.x * 128;
    const int t = threadIdx.x;
    const int w = t >> 6, l = t & 63;
    const int lr = l & 15, lg = l >> 4;
    const int q0w = q0 + w * 32;

    const unsigned short* Qp = Qw + (size_t)bh * S_ * HD_;
    const unsigned short* Kp = Kw + (size_t)bh * S_ * HD_;
    const unsigned short* Vp = Vt + (size_t)bh * HD_ * S_;

    // Q fragments: 2 row-tiles x 2 k-frags
    bfx8 qf[2][2];
#pragma unroll
    for (int r = 0; r < 2; ++r)
#pragma unroll
        for (int kk = 0; kk < 2; ++kk)
            qf[r][kk] = *(const bfx8*)&Qp[(size_t)(q0w + r * 16 + lr) * HD_ + kk * 32 + lg * 8];

    fx4 oacc[2][4] = {};
    float mrow[2][4], lsum[2][4];
#pragma unroll
    for (int r = 0; r < 2; ++r)
#pragma unroll
        for (int i = 0; i < 4; ++i) { mrow[r][i] = -1e30f; lsum[r][i] = 0.f; }

    const int nt = q0 / 64 + 2;   // kv tiles covering rows q0..q0+127

    // ---- prologue: stage tile 0 into buf 0 ----
    {
        bfx8 sreg[4];
#pragma unroll
        for (int it = 0; it < 4; ++it) {
            int id = t + 256 * it;          // 1024 chunks of 16B (K:0..511, V:512..1023)
            int c = id & 511;
            int row = c >> 3, q = c & 7;
            if (id < 512) sreg[it] = *(const bfx8*)&Kp[(size_t)row * HD_ + q * 8];
            else          sreg[it] = *(const bfx8*)&Vp[(size_t)row * S_ + q * 8];
        }
#pragma unroll
        for (int it = 0; it < 4; ++it) {
            int id = t + 256 * it;
            int c = id & 511;
            int row = c >> 3, q = c & 7;
            int off = row * 128 + ((q * 16) ^ ((row & 7) << 4));
            char* base = (id < 512) ? (char*)&Kl[0][0] : (char*)&Vl[0][0];
            *(bfx8*)(base + off) = sreg[it];
        }
    }
    __syncthreads();

    int buf = 0;
    for (int tkv = 0; tkv < nt; ++tkv) {
        const int kv0 = tkv * 64;
        const bool pre = (tkv + 1 < nt);
        // ---- issue next tile's global loads early (latency hides under compute) ----
        bfx8 sreg[4];
        if (pre) {
            const int kn = kv0 + 64;
#pragma unroll
            for (int it = 0; it < 4; ++it) {
                int id = t + 256 * it;
                int c = id & 511;
                int row = c >> 3, q = c & 7;
                if (id < 512) sreg[it] = *(const bfx8*)&Kp[(size_t)(kn + row) * HD_ + q * 8];
                else          sreg[it] = *(const bfx8*)&Vp[(size_t)row * S_ + kn + q * 8];
            }
        }
        // ---- compute on buf ----
#pragma unroll
        for (int r = 0; r < 2; ++r) {
            const int qr = q0w + r * 16;
            if (kv0 > qr + 15) continue;   // tile fully above diagonal for these rows
            // S = Q K^T
            fx4 sacc[4] = {};
#pragma unroll
            for (int c = 0; c < 4; ++c) {
                int row = c * 16 + lr;
#pragma unroll
                for (int kk = 0; kk < 2; ++kk) {
                    int colb = kk * 64 + lg * 16;
                    bfx8 kf = *(const bfx8*)((const char*)&Kl[buf][0] + row * 128 + (colb ^ ((row & 7) << 4)));
                    sacc[c] = __builtin_amdgcn_mfma_f32_16x16x32_bf16(qf[r][kk], kf, sacc[c], 0, 0, 0);
                }
            }
            // causal mask (only diagonal-straddling tiles)
            if (kv0 + 63 > qr) {
#pragma unroll
                for (int c = 0; c < 4; ++c)
#pragma unroll
                    for (int i = 0; i < 4; ++i)
                        if (kv0 + c * 16 + lr > qr + lg * 4 + i) sacc[c][i] = -1e30f;
            }
            // online softmax (rows = lane-group x reg; 16-lane reduce)
            float alpha[4];
#pragma unroll
            for (int i = 0; i < 4; ++i) {
                float mx = fmaxf(fmaxf(sacc[0][i], sacc[1][i]), fmaxf(sacc[2][i], sacc[3][i]));
                mx = fmaxf(mx, __shfl_xor(mx, 1));
                mx = fmaxf(mx, __shfl_xor(mx, 2));
                mx = fmaxf(mx, __shfl_xor(mx, 4));
                mx = fmaxf(mx, __shfl_xor(mx, 8));
                float mnew = fmaxf(mrow[r][i], mx);
                alpha[i] = exp2f(mrow[r][i] - mnew);
                mrow[r][i] = mnew;
            }
            float psum[4] = {0.f, 0.f, 0.f, 0.f};
#pragma unroll
            for (int c = 0; c < 4; ++c)
#pragma unroll
                for (int i = 0; i < 4; ++i) {
                    float p = exp2f(sacc[c][i] - mrow[r][i]);
                    psum[i] += p;
                    Pl[w][(r * 16 + lg * 4 + i) * 72 + c * 16 + lr] = f2bf(p);
                }
#pragma unroll
            for (int i = 0; i < 4; ++i) {
                float s = psum[i];
                s += __shfl_xor(s, 1);
                s += __shfl_xor(s, 2);
                s += __shfl_xor(s, 4);
                s += __shfl_xor(s, 8);
                lsum[r][i] = lsum[r][i] * alpha[i] + s;
            }
#pragma unroll
            for (int c = 0; c < 4; ++c)
#pragma unroll
                for (int i = 0; i < 4; ++i) oacc[r][c][i] *= alpha[i];
            // O += P V  (P A-frag from LDS, V^T B-frag from swizzled LDS)
#pragma unroll
            for (int kk = 0; kk < 2; ++kk) {
                bfx8 pf = *(const bfx8*)&Pl[w][(r * 16 + lr) * 72 + kk * 32 + lg * 8];
#pragma unroll
                for (int c = 0; c < 4; ++c) {
                    int vrow = c * 16 + lr;
                    int vcolb = kk * 64 + lg * 16;
                    bfx8 vf = *(const bfx8*)((const char*)&Vl[buf][0] + vrow * 128 + (vcolb ^ ((vrow & 7) << 4)));
                    oacc[r][c] = __builtin_amdgcn_mfma_f32_16x16x32_bf16(pf, vf, oacc[r][c], 0, 0, 0);
                }
            }
        }
        // ---- write staged regs to the other buffer (readers finished at prev barrier) ----
        if (pre) {
#pragma unroll
            for (int it = 0; it < 4; ++it) {
                int id = t + 256 * it;
                int c = id & 511;
                int row = c >> 3, q = c & 7;
                int off = row * 128 + ((q * 16) ^ ((row & 7) << 4));
                char* base = (id < 512) ? (char*)&Kl[buf ^ 1][0] : (char*)&Vl[buf ^ 1][0];
                *(bfx8*)(base + off) = sreg[it];
            }
        }
        __syncthreads();
        buf ^= 1;
    }

    // ---- write attn output bf16 [b][s][h*64+d] ----
    const int b = bh >> 4, h = bh & 15;
#pragma unroll
    for (int r = 0; r < 2; ++r)
#pragma unroll
        for (int c = 0; c < 4; ++c)
#pragma unroll
            for (int i = 0; i < 4; ++i) {
                int srow = q0w + r * 16 + lg * 4 + i;
                int col = h * 64 + c * 16 + lr;
                Ob[((size_t)b * S_ + srow) * D_ + col] = f2bf(oacc[r][c][i] / lsum[r][i]);
            }
}

// ---------------- out-proj GEMM: [8192,1024] x [1024,1024] + bias, f32 out ----------------
__launch_bounds__(256)
__global__ void k_gemm_proj(const unsigned short* __restrict__ A,
                            const unsigned short* __restrict__ Bt,
                            const float* __restrict__ bias,
                            float* __restrict__ out) {
    __shared__ unsigned short Al[128 * BK];
    __shared__ unsigned short Bl[128 * BK];
    const int m0 = blockIdx.y * 128;
    const int n0 = blockIdx.x * 128;
    const int t = threadIdx.x;
    const int w = t >> 6, l = t & 63;
    const int wr = w >> 1, wc = w & 1;
    const int lr = l & 15, lg = l >> 4;
    fx4 acc[4][4] = {};

    for (int k0 = 0; k0 < D_; k0 += BK) {
        __syncthreads();
#pragma unroll
        for (int j = 0; j < 2; ++j) {
            int id = t + 256 * j;
            int row = id >> 2, q = id & 3;
            *(bfx8*)&Al[row * BK + q * 8] = *(const bfx8*)&A [(size_t)(m0 + row) * D_ + k0 + q * 8];
            *(bfx8*)&Bl[row * BK + q * 8] = *(const bfx8*)&Bt[(size_t)(n0 + row) * D_ + k0 + q * 8];
        }
        __syncthreads();
        bfx8 af[4], bf[4];
#pragma unroll
        for (int i = 0; i < 4; ++i) af[i] = *(const bfx8*)&Al[(wr * 64 + i * 16 + lr) * BK + lg * 8];
#pragma unroll
        for (int i = 0; i < 4; ++i) bf[i] = *(const bfx8*)&Bl[(wc * 64 + i * 16 + lr) * BK + lg * 8];
#pragma unroll
        for (int mi = 0; mi < 4; ++mi)
#pragma unroll
            for (int ni = 0; ni < 4; ++ni)
                acc[mi][ni] = __builtin_amdgcn_mfma_f32_16x16x32_bf16(af[mi], bf[ni], acc[mi][ni], 0, 0, 0);
    }
#pragma unroll
    for (int ni = 0; ni < 4; ++ni) {
        int col = n0 + wc * 64 + ni * 16 + lr;
        float bv = bias[col];
#pragma unroll
        for (int mi = 0; mi < 4; ++mi)
#pragma unroll
            for (int i = 0; i < 4; ++i) {
                int m = m0 + wr * 64 + mi * 16 + lg * 4 + i;
                out[(size_t)m * D_ + col] = acc[mi][ni][i] + bv;
            }
    }
}

extern "C" void kernel_launch(void* const* d_in, const int* in_sizes, int n_in,
                              void* d_out, int out_size, void* d_ws, size_t ws_size,
                              hipStream_t stream) {
    const float* x     = (const float*)d_in[0];
    const float* w_qkv = (const float*)d_in[1];
    const float* b_qkv = (const float*)d_in[2];
    const float* w_out = (const float*)d_in[3];
    const float* b_out = (const float*)d_in[4];
    float* out = (float*)d_out;

    unsigned short* xb    = (unsigned short*)d_ws;          // 8192*1024
    unsigned short* wqkvT = xb    + (size_t)MTOK * D_;      // 3072*1024
    unsigned short* woutT = wqkvT + (size_t)3 * D_ * D_;    // 1024*1024
    unsigned short* Qw    = woutT + (size_t)D_ * D_;        // 8192*1024
    unsigned short* Kw    = Qw    + (size_t)MTOK * D_;
    unsigned short* Vt    = Kw    + (size_t)MTOK * D_;
    unsigned short* attnb = Vt    + (size_t)MTOK * D_;

    k_conv_x<<<2048, 256, 0, stream>>>(x, xb, MTOK * D_ / 8);
    k_transpose_bf<<<(3 * D_ * (D_ / 8)) / 256, 256, 0, stream>>>(w_qkv, wqkvT, D_, 3 * D_);
    k_transpose_bf<<<(D_ * (D_ / 8)) / 256, 256, 0, stream>>>(w_out, woutT, D_, D_);
    k_gemm_qkv<<<dim3(24, 64), 256, 0, stream>>>(xb, wqkvT, b_qkv, Qw, Kw, Vt);
    k_attn<<<dim3(S_ / 128, B_ * H_), 256, 0, stream>>>(Qw, Kw, Vt, attnb);
    k_gemm_proj<<<dim3(8, 64), 256, 0, stream>>>(attnb, woutT, b_out, out);
}

// Round 3
// 290.388 us; speedup vs baseline: 2.1632x; 1.4243x over previous
//
#include <hip/hip_runtime.h>
#include <hip/hip_bf16.h>
#include <stdint.h>

// CausalSelfAttention: B=4 S=2048 D=1024 H=16 hd=64
// Pipeline: conv(x,wT) -> QKV gemm (bf16 mfma, epilogue scatters Q,K,V^T)
//           -> flash attention (paired q-tiles for balance, LDS K/V, online softmax)
//           -> out-proj gemm (f32 out + bias)

#define B_   4
#define S_   2048
#define D_   1024
#define H_   16
#define HD_  64
#define MTOK (B_ * S_)   // 8192

typedef __attribute__((ext_vector_type(8))) short bfx8;
typedef __attribute__((ext_vector_type(4))) float fx4;

static __device__ __forceinline__ unsigned short f2bf(float f) {
    union { float f; uint32_t u; } v{f};
    uint32_t u = v.u;
    u += 0x7fffu + ((u >> 16) & 1u);   // RNE
    return (unsigned short)(u >> 16);
}

// ---------------- convert x f32 -> bf16 ----------------
__global__ void k_conv_x(const float* __restrict__ x, unsigned short* __restrict__ xb, int n8) {
    int i = blockIdx.x * blockDim.x + threadIdx.x;
    int stride = gridDim.x * blockDim.x;
    for (; i < n8; i += stride) {
        const float4* p = (const float4*)(x + (size_t)i * 8);
        float4 a = p[0], b = p[1];
        bfx8 o;
        o[0]=f2bf(a.x); o[1]=f2bf(a.y); o[2]=f2bf(a.z); o[3]=f2bf(a.w);
        o[4]=f2bf(b.x); o[5]=f2bf(b.y); o[6]=f2bf(b.z); o[7]=f2bf(b.w);
        *(bfx8*)(xb + (size_t)i * 8) = o;
    }
}

// ---------------- transpose W [K][N] f32 -> Wt [N][K] bf16 ----------------
__global__ void k_transpose_bf(const float* __restrict__ w, unsigned short* __restrict__ wt,
                               int K, int N) {
    int idx = blockIdx.x * blockDim.x + threadIdx.x;
    int total = N * (K / 8);
    if (idx >= total) return;
    int n  = idx % N;
    int k0 = (idx / N) * 8;
    bfx8 o;
#pragma unroll
    for (int j = 0; j < 8; ++j) o[j] = f2bf(w[(size_t)(k0 + j) * N + n]);
    *(bfx8*)(wt + (size_t)n * K + k0) = o;
}

// ---------------- QKV GEMM: [8192,1024] x [1024,3072] ----------------
#define BK 32
#define QSCALE 0.18033688011112042f   // 0.125 * log2(e)

__launch_bounds__(256)
__global__ void k_gemm_qkv(const unsigned short* __restrict__ A,
                           const unsigned short* __restrict__ Bt,
                           const float* __restrict__ bias,
                           unsigned short* __restrict__ Qw,
                           unsigned short* __restrict__ Kw,
                           unsigned short* __restrict__ Vt) {
    __shared__ unsigned short Al[128 * BK];
    __shared__ unsigned short Bl[128 * BK];
    const int m0 = blockIdx.y * 128;
    const int n0 = blockIdx.x * 128;
    const int t = threadIdx.x;
    const int w = t >> 6, l = t & 63;
    const int wr = w >> 1, wc = w & 1;
    const int lr = l & 15, lg = l >> 4;
    fx4 acc[4][4] = {};

    for (int k0 = 0; k0 < D_; k0 += BK) {
        __syncthreads();
#pragma unroll
        for (int j = 0; j < 2; ++j) {
            int id = t + 256 * j;
            int row = id >> 2, q = id & 3;
            *(bfx8*)&Al[row * BK + q * 8] = *(const bfx8*)&A [(size_t)(m0 + row) * D_ + k0 + q * 8];
            *(bfx8*)&Bl[row * BK + q * 8] = *(const bfx8*)&Bt[(size_t)(n0 + row) * D_ + k0 + q * 8];
        }
        __syncthreads();
        bfx8 af[4], bf[4];
#pragma unroll
        for (int i = 0; i < 4; ++i) af[i] = *(const bfx8*)&Al[(wr * 64 + i * 16 + lr) * BK + lg * 8];
#pragma unroll
        for (int i = 0; i < 4; ++i) bf[i] = *(const bfx8*)&Bl[(wc * 64 + i * 16 + lr) * BK + lg * 8];
#pragma unroll
        for (int mi = 0; mi < 4; ++mi)
#pragma unroll
            for (int ni = 0; ni < 4; ++ni)
                acc[mi][ni] = __builtin_amdgcn_mfma_f32_16x16x32_bf16(af[mi], bf[ni], acc[mi][ni], 0, 0, 0);
    }

    const int colbase = n0 + wc * 64;
    const int mat = colbase >> 10;
#pragma unroll
    for (int ni = 0; ni < 4; ++ni) {
        int col = colbase + ni * 16 + lr;
        int dcol = col & 1023;
        int h = dcol >> 6, dd = dcol & 63;
        float bv = bias[col];
#pragma unroll
        for (int mi = 0; mi < 4; ++mi) {
#pragma unroll
            for (int i = 0; i < 4; ++i) {
                int m = m0 + wr * 64 + mi * 16 + lg * 4 + i;
                int b = m >> 11, s = m & 2047;
                float v = acc[mi][ni][i] + bv;
                int bh = b * H_ + h;
                if (mat == 0)      Qw[((size_t)bh * S_ + s) * HD_ + dd] = f2bf(v * QSCALE);
                else if (mat == 1) Kw[((size_t)bh * S_ + s) * HD_ + dd] = f2bf(v);
                else               Vt[((size_t)bh * HD_ + dd) * S_ + s] = f2bf(v);
            }
        }
    }
}

// ---------------- flash attention ----------------
// 8 waves/block, 16 rows/wave per stream. Each block handles q-tiles (pi, 15-pi):
// the small tile's kv range is a subset of the big one's, so one staging stream
// serves both and every block does exactly 34 wave-units -> perfect balance.
__launch_bounds__(512, 4)
__global__ void k_attn(const unsigned short* __restrict__ Qw,
                       const unsigned short* __restrict__ Kw,
                       const unsigned short* __restrict__ Vt,
                       unsigned short* __restrict__ Ob) {
    __shared__ unsigned short Kl[2][64 * 64];   // [kv][d], row=128B, XOR-swizzled
    __shared__ unsigned short Vl[2][64 * 64];   // [d][kv], row=128B, XOR-swizzled
    __shared__ unsigned short Pl[8][16 * 72];   // per-wave P, padded stride 72
    const int bh = blockIdx.y;
    const int pi = blockIdx.x;                  // 0..7
    const int t = threadIdx.x;
    const int w = t >> 6, l = t & 63;
    const int lr = l & 15, lg = l >> 4;
    const int qA = pi * 128 + w * 16;           // small stream
    const int qB = (15 - pi) * 128 + w * 16;    // big stream
    const int NT = 32 - 2 * pi;                 // staged kv tiles (covers B)

    const unsigned short* Qp = Qw + (size_t)bh * S_ * HD_;
    const unsigned short* Kp = Kw + (size_t)bh * S_ * HD_;
    const unsigned short* Vp = Vt + (size_t)bh * HD_ * S_;

    bfx8 qfA[2], qfB[2];
#pragma unroll
    for (int kk = 0; kk < 2; ++kk) {
        qfA[kk] = *(const bfx8*)&Qp[(size_t)(qA + lr) * HD_ + kk * 32 + lg * 8];
        qfB[kk] = *(const bfx8*)&Qp[(size_t)(qB + lr) * HD_ + kk * 32 + lg * 8];
    }

    fx4 oA[4] = {}, oB[4] = {};
    float mA[4], lA[4], mB[4], lB[4];
#pragma unroll
    for (int i = 0; i < 4; ++i) { mA[i] = mB[i] = -1e30f; lA[i] = lB[i] = 0.f; }

    // one stream's per-tile compute (QK^T -> online softmax -> PV)
    auto compute = [&](int qr, const bfx8* qf, fx4* oacc, float* mrow, float* lsum,
                       int kv0, int buf) {
        fx4 sacc[4] = {};
#pragma unroll
        for (int c = 0; c < 4; ++c) {
            int row = c * 16 + lr;
#pragma unroll
            for (int kk = 0; kk < 2; ++kk) {
                int colb = kk * 64 + lg * 16;
                bfx8 kf = *(const bfx8*)((const char*)&Kl[buf][0] + row * 128 + (colb ^ ((row & 7) << 4)));
                sacc[c] = __builtin_amdgcn_mfma_f32_16x16x32_bf16(qf[kk], kf, sacc[c], 0, 0, 0);
            }
        }
        if (kv0 + 63 > qr) {
#pragma unroll
            for (int c = 0; c < 4; ++c)
#pragma unroll
                for (int i = 0; i < 4; ++i)
                    if (kv0 + c * 16 + lr > qr + lg * 4 + i) sacc[c][i] = -1e30f;
        }
        float alpha[4];
#pragma unroll
        for (int i = 0; i < 4; ++i) {
            float mx = fmaxf(fmaxf(sacc[0][i], sacc[1][i]), fmaxf(sacc[2][i], sacc[3][i]));
            mx = fmaxf(mx, __shfl_xor(mx, 1));
            mx = fmaxf(mx, __shfl_xor(mx, 2));
            mx = fmaxf(mx, __shfl_xor(mx, 4));
            mx = fmaxf(mx, __shfl_xor(mx, 8));
            float mnew = fmaxf(mrow[i], mx);
            alpha[i] = exp2f(mrow[i] - mnew);
            mrow[i] = mnew;
        }
        float psum[4] = {0.f, 0.f, 0.f, 0.f};
#pragma unroll
        for (int c = 0; c < 4; ++c)
#pragma unroll
            for (int i = 0; i < 4; ++i) {
                float p = exp2f(sacc[c][i] - mrow[i]);
                psum[i] += p;
                Pl[w][(lg * 4 + i) * 72 + c * 16 + lr] = f2bf(p);
            }
#pragma unroll
        for (int i = 0; i < 4; ++i) {
            float s = psum[i];
            s += __shfl_xor(s, 1);
            s += __shfl_xor(s, 2);
            s += __shfl_xor(s, 4);
            s += __shfl_xor(s, 8);
            lsum[i] = lsum[i] * alpha[i] + s;
        }
#pragma unroll
        for (int c = 0; c < 4; ++c)
#pragma unroll
            for (int i = 0; i < 4; ++i) oacc[c][i] *= alpha[i];
#pragma unroll
        for (int kk = 0; kk < 2; ++kk) {
            bfx8 pf = *(const bfx8*)&Pl[w][lr * 72 + kk * 32 + lg * 8];
#pragma unroll
            for (int c = 0; c < 4; ++c) {
                int vrow = c * 16 + lr;
                int vcolb = kk * 64 + lg * 16;
                bfx8 vf = *(const bfx8*)((const char*)&Vl[buf][0] + vrow * 128 + (vcolb ^ ((vrow & 7) << 4)));
                oacc[c] = __builtin_amdgcn_mfma_f32_16x16x32_bf16(pf, vf, oacc[c], 0, 0, 0);
            }
        }
    };

    // ---- prologue: stage tile 0 into buf 0 (1024 chunks of 16B, 512 threads) ----
    {
        bfx8 sreg[2];
#pragma unroll
        for (int it = 0; it < 2; ++it) {
            int id = t + 512 * it;
            int c = id & 511;
            int row = c >> 3, q = c & 7;
            if (id < 512) sreg[it] = *(const bfx8*)&Kp[(size_t)row * HD_ + q * 8];
            else          sreg[it] = *(const bfx8*)&Vp[(size_t)row * S_ + q * 8];
        }
#pragma unroll
        for (int it = 0; it < 2; ++it) {
            int id = t + 512 * it;
            int c = id & 511;
            int row = c >> 3, q = c & 7;
            int off = row * 128 + ((q * 16) ^ ((row & 7) << 4));
            char* base = (id < 512) ? (char*)&Kl[0][0] : (char*)&Vl[0][0];
            *(bfx8*)(base + off) = sreg[it];
        }
    }
    __syncthreads();

    int buf = 0;
    for (int tkv = 0; tkv < NT; ++tkv) {
        const int kv0 = tkv * 64;
        const bool pre = (tkv + 1 < NT);
        bfx8 sreg[2];
        if (pre) {
            const int kn = kv0 + 64;
#pragma unroll
            for (int it = 0; it < 2; ++it) {
                int id = t + 512 * it;
                int c = id & 511;
                int row = c >> 3, q = c & 7;
                if (id < 512) sreg[it] = *(const bfx8*)&Kp[(size_t)(kn + row) * HD_ + q * 8];
                else          sreg[it] = *(const bfx8*)&Vp[(size_t)row * S_ + kn + q * 8];
            }
        }
        if (kv0 <= qB + 15) compute(qB, qfB, oB, mB, lB, kv0, buf);
        if (kv0 <= qA + 15) compute(qA, qfA, oA, mA, lA, kv0, buf);
        if (pre) {
#pragma unroll
            for (int it = 0; it < 2; ++it) {
                int id = t + 512 * it;
                int c = id & 511;
                int row = c >> 3, q = c & 7;
                int off = row * 128 + ((q * 16) ^ ((row & 7) << 4));
                char* base = (id < 512) ? (char*)&Kl[buf ^ 1][0] : (char*)&Vl[buf ^ 1][0];
                *(bfx8*)(base + off) = sreg[it];
            }
        }
        __syncthreads();
        buf ^= 1;
    }

    // ---- outputs: bf16 [b][s][h*64+d] for both streams ----
    const int b = bh >> 4, h = bh & 15;
#pragma unroll
    for (int c = 0; c < 4; ++c)
#pragma unroll
        for (int i = 0; i < 4; ++i) {
            int col = h * 64 + c * 16 + lr;
            int sA = qA + lg * 4 + i;
            int sB = qB + lg * 4 + i;
            Ob[((size_t)b * S_ + sA) * D_ + col] = f2bf(oA[c][i] / lA[i]);
            Ob[((size_t)b * S_ + sB) * D_ + col] = f2bf(oB[c][i] / lB[i]);
        }
}

// ---------------- out-proj GEMM: [8192,1024] x [1024,1024] + bias, f32 out ----------------
__launch_bounds__(256)
__global__ void k_gemm_proj(const unsigned short* __restrict__ A,
                            const unsigned short* __restrict__ Bt,
                            const float* __restrict__ bias,
                            float* __restrict__ out) {
    __shared__ unsigned short Al[128 * BK];
    __shared__ unsigned short Bl[128 * BK];
    const int m0 = blockIdx.y * 128;
    const int n0 = blockIdx.x * 128;
    const int t = threadIdx.x;
    const int w = t >> 6, l = t & 63;
    const int wr = w >> 1, wc = w & 1;
    const int lr = l & 15, lg = l >> 4;
    fx4 acc[4][4] = {};

    for (int k0 = 0; k0 < D_; k0 += BK) {
        __syncthreads();
#pragma unroll
        for (int j = 0; j < 2; ++j) {
            int id = t + 256 * j;
            int row = id >> 2, q = id & 3;
            *(bfx8*)&Al[row * BK + q * 8] = *(const bfx8*)&A [(size_t)(m0 + row) * D_ + k0 + q * 8];
            *(bfx8*)&Bl[row * BK + q * 8] = *(const bfx8*)&Bt[(size_t)(n0 + row) * D_ + k0 + q * 8];
        }
        __syncthreads();
        bfx8 af[4], bf[4];
#pragma unroll
        for (int i = 0; i < 4; ++i) af[i] = *(const bfx8*)&Al[(wr * 64 + i * 16 + lr) * BK + lg * 8];
#pragma unroll
        for (int i = 0; i < 4; ++i) bf[i] = *(const bfx8*)&Bl[(wc * 64 + i * 16 + lr) * BK + lg * 8];
#pragma unroll
        for (int mi = 0; mi < 4; ++mi)
#pragma unroll
            for (int ni = 0; ni < 4; ++ni)
                acc[mi][ni] = __builtin_amdgcn_mfma_f32_16x16x32_bf16(af[mi], bf[ni], acc[mi][ni], 0, 0, 0);
    }
#pragma unroll
    for (int ni = 0; ni < 4; ++ni) {
        int col = n0 + wc * 64 + ni * 16 + lr;
        float bv = bias[col];
#pragma unroll
        for (int mi = 0; mi < 4; ++mi)
#pragma unroll
            for (int i = 0; i < 4; ++i) {
                int m = m0 + wr * 64 + mi * 16 + lg * 4 + i;
                out[(size_t)m * D_ + col] = acc[mi][ni][i] + bv;
            }
    }
}

extern "C" void kernel_launch(void* const* d_in, const int* in_sizes, int n_in,
                              void* d_out, int out_size, void* d_ws, size_t ws_size,
                              hipStream_t stream) {
    const float* x     = (const float*)d_in[0];
    const float* w_qkv = (const float*)d_in[1];
    const float* b_qkv = (const float*)d_in[2];
    const float* w_out = (const float*)d_in[3];
    const float* b_out = (const float*)d_in[4];
    float* out = (float*)d_out;

    unsigned short* xb    = (unsigned short*)d_ws;          // 8192*1024
    unsigned short* wqkvT = xb    + (size_t)MTOK * D_;      // 3072*1024
    unsigned short* woutT = wqkvT + (size_t)3 * D_ * D_;    // 1024*1024
    unsigned short* Qw    = woutT + (size_t)D_ * D_;        // 8192*1024
    unsigned short* Kw    = Qw    + (size_t)MTOK * D_;
    unsigned short* Vt    = Kw    + (size_t)MTOK * D_;
    unsigned short* attnb = Vt    + (size_t)MTOK * D_;

    k_conv_x<<<2048, 256, 0, stream>>>(x, xb, MTOK * D_ / 8);
    k_transpose_bf<<<(3 * D_ * (D_ / 8)) / 256, 256, 0, stream>>>(w_qkv, wqkvT, D_, 3 * D_);
    k_transpose_bf<<<(D_ * (D_ / 8)) / 256, 256, 0, stream>>>(w_out, woutT, D_, D_);
    k_gemm_qkv<<<dim3(24, 64), 256, 0, stream>>>(xb, wqkvT, b_qkv, Qw, Kw, Vt);
    k_attn<<<dim3(8, B_ * H_), 512, 0, stream>>>(Qw, Kw, Vt, attnb);
    k_gemm_proj<<<dim3(8, 64), 256, 0, stream>>>(attnb, woutT, b_out, out);
}

// Round 4
// 235.970 us; speedup vs baseline: 2.6621x; 1.2306x over previous
//
#include <hip/hip_runtime.h>
#include <hip/hip_bf16.h>
#include <stdint.h>

// CausalSelfAttention: B=4 S=2048 D=1024 H=16 hd=64
// conv(x) -> QKV gemm (global_load_lds, BK=64) -> flash attn (swapped QK^T,
// lane-local softmax, cvt_pk P) -> out-proj gemm

#define B_   4
#define S_   2048
#define D_   1024
#define H_   16
#define HD_  64
#define MTOK (B_ * S_)   // 8192

typedef __attribute__((ext_vector_type(8))) short bfx8;
typedef __attribute__((ext_vector_type(4))) float fx4;

static __device__ __forceinline__ unsigned short f2bf(float f) {
    union { float f; uint32_t u; } v{f};
    uint32_t u = v.u;
    u += 0x7fffu + ((u >> 16) & 1u);   // RNE
    return (unsigned short)(u >> 16);
}

static __device__ __forceinline__ uint32_t cvtpk(float lo, float hi) {
    uint32_t r;
    asm volatile("v_cvt_pk_bf16_f32 %0, %1, %2" : "=v"(r) : "v"(lo), "v"(hi));
    return r;
}

// global -> LDS direct DMA, 16B per lane; LDS dest = wave-uniform base + lane*16
static __device__ __forceinline__ void gll16(const unsigned short* g, const unsigned short* l) {
    typedef const __attribute__((address_space(1))) void* gp_t;
    typedef __attribute__((address_space(3))) void* lp_t;
    __builtin_amdgcn_global_load_lds((gp_t)(uintptr_t)g, (lp_t)(uint32_t)(uintptr_t)l, 16, 0, 0);
}

// ---------------- convert x f32 -> bf16 ----------------
__global__ void k_conv_x(const float* __restrict__ x, unsigned short* __restrict__ xb, int n8) {
    int i = blockIdx.x * blockDim.x + threadIdx.x;
    int stride = gridDim.x * blockDim.x;
    for (; i < n8; i += stride) {
        const float4* p = (const float4*)(x + (size_t)i * 8);
        float4 a = p[0], b = p[1];
        bfx8 o;
        o[0]=f2bf(a.x); o[1]=f2bf(a.y); o[2]=f2bf(a.z); o[3]=f2bf(a.w);
        o[4]=f2bf(b.x); o[5]=f2bf(b.y); o[6]=f2bf(b.z); o[7]=f2bf(b.w);
        *(bfx8*)(xb + (size_t)i * 8) = o;
    }
}

// ---------------- transpose W [K][N] f32 -> Wt [N][K] bf16 ----------------
__global__ void k_transpose_bf(const float* __restrict__ w, unsigned short* __restrict__ wt,
                               int K, int N) {
    int idx = blockIdx.x * blockDim.x + threadIdx.x;
    int total = N * (K / 8);
    if (idx >= total) return;
    int n  = idx % N;
    int k0 = (idx / N) * 8;
    bfx8 o;
#pragma unroll
    for (int j = 0; j < 8; ++j) o[j] = f2bf(w[(size_t)(k0 + j) * N + n]);
    *(bfx8*)(wt + (size_t)n * K + k0) = o;
}

// ---------------- QKV GEMM: [8192,1024] x [1024,3072], BK=64, global_load_lds ----------------
#define GBK 64
#define QSCALE 0.18033688011112042f   // 0.125 * log2(e)

__launch_bounds__(256)
__global__ void k_gemm_qkv(const unsigned short* __restrict__ A,
                           const unsigned short* __restrict__ Bt,
                           const float* __restrict__ bias,
                           unsigned short* __restrict__ Qw,
                           unsigned short* __restrict__ Kw,
                           unsigned short* __restrict__ Vt) {
    __shared__ unsigned short Al[128 * GBK];   // [row][64] linear, 16KB
    __shared__ unsigned short Bl[128 * GBK];
    const int m0 = blockIdx.y * 128;
    const int n0 = blockIdx.x * 128;
    const int t = threadIdx.x;
    const int w = t >> 6, l = t & 63;
    const int wr = w >> 1, wc = w & 1;
    const int lr = l & 15, lg = l >> 4;
    const int srow = w * 32 + (l >> 3);        // staging row base (this wave: rows w*32..w*32+31)
    const int scol = (l & 7) * 8;              // staging col (elems)
    fx4 acc[4][4] = {};

    for (int k0 = 0; k0 < D_; k0 += GBK) {
        __syncthreads();
#pragma unroll
        for (int j = 0; j < 4; ++j) {          // 4 chunks A + 4 chunks B per wave, 1KB each
            gll16(&A [(size_t)(m0 + srow + j * 8) * D_ + k0 + scol], &Al[(w * 32 + j * 8) * GBK]);
            gll16(&Bt[(size_t)(n0 + srow + j * 8) * D_ + k0 + scol], &Bl[(w * 32 + j * 8) * GBK]);
        }
        __syncthreads();
#pragma unroll
        for (int kk = 0; kk < 2; ++kk) {
            bfx8 af[4], bf[4];
#pragma unroll
            for (int i = 0; i < 4; ++i) af[i] = *(const bfx8*)&Al[(wr * 64 + i * 16 + lr) * GBK + kk * 32 + lg * 8];
#pragma unroll
            for (int i = 0; i < 4; ++i) bf[i] = *(const bfx8*)&Bl[(wc * 64 + i * 16 + lr) * GBK + kk * 32 + lg * 8];
#pragma unroll
            for (int mi = 0; mi < 4; ++mi)
#pragma unroll
                for (int ni = 0; ni < 4; ++ni)
                    acc[mi][ni] = __builtin_amdgcn_mfma_f32_16x16x32_bf16(af[mi], bf[ni], acc[mi][ni], 0, 0, 0);
        }
    }

    const int colbase = n0 + wc * 64;
    const int mat = colbase >> 10;
#pragma unroll
    for (int ni = 0; ni < 4; ++ni) {
        int col = colbase + ni * 16 + lr;
        int dcol = col & 1023;
        int h = dcol >> 6, dd = dcol & 63;
        float bv = bias[col];
#pragma unroll
        for (int mi = 0; mi < 4; ++mi) {
#pragma unroll
            for (int i = 0; i < 4; ++i) {
                int m = m0 + wr * 64 + mi * 16 + lg * 4 + i;
                int b = m >> 11, s = m & 2047;
                float v = acc[mi][ni][i] + bv;
                int bh = b * H_ + h;
                if (mat == 0)      Qw[((size_t)bh * S_ + s) * HD_ + dd] = f2bf(v * QSCALE);
                else if (mat == 1) Kw[((size_t)bh * S_ + s) * HD_ + dd] = f2bf(v);
                else               Vt[((size_t)bh * HD_ + dd) * S_ + s] = f2bf(v);
            }
        }
    }
}

// ---------------- flash attention (swapped QK^T, lane-local softmax) ----------------
// 8 waves, paired q-tiles (pi, 15-pi), kv tile 64, K/V LDS double-buffered + swizzled.
// S^T = mfma(K,Q): lane holds q = qr+lr (fixed), kv = 16c+lg*4+i.
__launch_bounds__(512, 4)
__global__ void k_attn(const unsigned short* __restrict__ Qw,
                       const unsigned short* __restrict__ Kw,
                       const unsigned short* __restrict__ Vt,
                       unsigned short* __restrict__ Ob) {
    __shared__ unsigned short Kl[2][64 * 64];   // [kv][d], row=128B, XOR-swizzled
    __shared__ unsigned short Vl[2][64 * 64];   // [d][kv], row=128B, XOR-swizzled
    __shared__ unsigned short Pl[8][16 * 72];   // per-wave P [q][kv], stride 72 elems
    const int bh = blockIdx.y;
    const int pi = blockIdx.x;                  // 0..7
    const int t = threadIdx.x;
    const int w = t >> 6, l = t & 63;
    const int lr = l & 15, lg = l >> 4;
    const int qA = pi * 128 + w * 16;
    const int qB = (15 - pi) * 128 + w * 16;
    const int NT = 32 - 2 * pi;

    const unsigned short* Qp = Qw + (size_t)bh * S_ * HD_;
    const unsigned short* Kp = Kw + (size_t)bh * S_ * HD_;
    const unsigned short* Vp = Vt + (size_t)bh * HD_ * S_;

    bfx8 qfA[2], qfB[2];
#pragma unroll
    for (int kk = 0; kk < 2; ++kk) {
        qfA[kk] = *(const bfx8*)&Qp[(size_t)(qA + lr) * HD_ + kk * 32 + lg * 8];
        qfB[kk] = *(const bfx8*)&Qp[(size_t)(qB + lr) * HD_ + kk * 32 + lg * 8];
    }

    fx4 oA[4] = {}, oB[4] = {};
    float mA = -1e30f, lA = 0.f, mB = -1e30f, lB = 0.f;

    auto compute = [&](int qr, const bfx8* qf, fx4* oacc, float& mrow, float& lsum,
                       int kv0, int buf) {
        // S^T = K . Q^T
        fx4 sacc[4] = {};
#pragma unroll
        for (int c = 0; c < 4; ++c) {
            int row = c * 16 + lr;
#pragma unroll
            for (int kk = 0; kk < 2; ++kk) {
                int colb = kk * 64 + lg * 16;
                bfx8 kf = *(const bfx8*)((const char*)&Kl[buf][0] + row * 128 + (colb ^ ((row & 7) << 4)));
                sacc[c] = __builtin_amdgcn_mfma_f32_16x16x32_bf16(kf, qf[kk], sacc[c], 0, 0, 0);
            }
        }
        // causal mask: lane's q-row = qr+lr; kv = kv0 + 16c + lg*4 + i
        if (kv0 + 63 > qr) {
            const int qrel = qr + lr - kv0;
#pragma unroll
            for (int c = 0; c < 4; ++c)
#pragma unroll
                for (int i = 0; i < 4; ++i)
                    if (c * 16 + lg * 4 + i > qrel) sacc[c][i] = -1e30f;
        }
        // row max: 15 local + 2 shuffles (groups share q when lr equal)
        float mc0 = fmaxf(fmaxf(sacc[0][0], sacc[0][1]), fmaxf(sacc[0][2], sacc[0][3]));
        float mc1 = fmaxf(fmaxf(sacc[1][0], sacc[1][1]), fmaxf(sacc[1][2], sacc[1][3]));
        float mc2 = fmaxf(fmaxf(sacc[2][0], sacc[2][1]), fmaxf(sacc[2][2], sacc[2][3]));
        float mc3 = fmaxf(fmaxf(sacc[3][0], sacc[3][1]), fmaxf(sacc[3][2], sacc[3][3]));
        float mx = fmaxf(fmaxf(mc0, mc1), fmaxf(mc2, mc3));
        mx = fmaxf(mx, __shfl_xor(mx, 16));
        mx = fmaxf(mx, __shfl_xor(mx, 32));
        float mnew = fmaxf(mrow, mx);
        float al = exp2f(mrow - mnew);
        mrow = mnew;
        // P = exp2(S-m), packed to bf16 pairs
        float ps = 0.f;
        uint32_t pk[4][2];
#pragma unroll
        for (int c = 0; c < 4; ++c)
#pragma unroll
            for (int r = 0; r < 2; ++r) {
                float p0 = exp2f(sacc[c][2 * r]     - mnew);
                float p1 = exp2f(sacc[c][2 * r + 1] - mnew);
                ps += p0 + p1;
                pk[c][r] = cvtpk(p0, p1);
            }
        ps += __shfl_xor(ps, 16);
        ps += __shfl_xor(ps, 32);
        lsum = lsum * al + ps;
        // store P[q][kv]: 4x ds_write_b64
#pragma unroll
        for (int c = 0; c < 4; ++c) {
            uint2 u; u.x = pk[c][0]; u.y = pk[c][1];
            *(uint2*)&Pl[w][lr * 72 + c * 16 + lg * 4] = u;
        }
#pragma unroll
        for (int c = 0; c < 4; ++c)
#pragma unroll
            for (int i = 0; i < 4; ++i) oacc[c][i] *= al;
        // O^T += V^T . P^T
#pragma unroll
        for (int kk = 0; kk < 2; ++kk) {
            bfx8 pf = *(const bfx8*)&Pl[w][lr * 72 + kk * 32 + lg * 8];
#pragma unroll
            for (int c = 0; c < 4; ++c) {
                int vrow = c * 16 + lr;
                int vcolb = kk * 64 + lg * 16;
                bfx8 vf = *(const bfx8*)((const char*)&Vl[buf][0] + vrow * 128 + (vcolb ^ ((vrow & 7) << 4)));
                oacc[c] = __builtin_amdgcn_mfma_f32_16x16x32_bf16(vf, pf, oacc[c], 0, 0, 0);
            }
        }
    };

    // ---- prologue: stage tile 0 into buf 0 ----
    {
        bfx8 sreg[2];
#pragma unroll
        for (int it = 0; it < 2; ++it) {
            int id = t + 512 * it;
            int c = id & 511;
            int row = c >> 3, q = c & 7;
            if (id < 512) sreg[it] = *(const bfx8*)&Kp[(size_t)row * HD_ + q * 8];
            else          sreg[it] = *(const bfx8*)&Vp[(size_t)row * S_ + q * 8];
        }
#pragma unroll
        for (int it = 0; it < 2; ++it) {
            int id = t + 512 * it;
            int c = id & 511;
            int row = c >> 3, q = c & 7;
            int off = row * 128 + ((q * 16) ^ ((row & 7) << 4));
            char* base = (id < 512) ? (char*)&Kl[0][0] : (char*)&Vl[0][0];
            *(bfx8*)(base + off) = sreg[it];
        }
    }
    __syncthreads();

    int buf = 0;
    for (int tkv = 0; tkv < NT; ++tkv) {
        const int kv0 = tkv * 64;
        const bool pre = (tkv + 1 < NT);
        bfx8 sreg[2];
        if (pre) {
            const int kn = kv0 + 64;
#pragma unroll
            for (int it = 0; it < 2; ++it) {
                int id = t + 512 * it;
                int c = id & 511;
                int row = c >> 3, q = c & 7;
                if (id < 512) sreg[it] = *(const bfx8*)&Kp[(size_t)(kn + row) * HD_ + q * 8];
                else          sreg[it] = *(const bfx8*)&Vp[(size_t)row * S_ + kn + q * 8];
            }
        }
        if (kv0 <= qB + 15) compute(qB, qfB, oB, mB, lB, kv0, buf);
        if (kv0 <= qA + 15) compute(qA, qfA, oA, mA, lA, kv0, buf);
        if (pre) {
#pragma unroll
            for (int it = 0; it < 2; ++it) {
                int id = t + 512 * it;
                int c = id & 511;
                int row = c >> 3, q = c & 7;
                int off = row * 128 + ((q * 16) ^ ((row & 7) << 4));
                char* base = (id < 512) ? (char*)&Kl[buf ^ 1][0] : (char*)&Vl[buf ^ 1][0];
                *(bfx8*)(base + off) = sreg[it];
            }
        }
        __syncthreads();
        buf ^= 1;
    }

    // ---- outputs: O^T lane layout -> packed 8B stores ----
    const int b = bh >> 4, h = bh & 15;
    const float ivA = __builtin_amdgcn_rcpf(lA);
    const float ivB = __builtin_amdgcn_rcpf(lB);
#pragma unroll
    for (int c = 0; c < 4; ++c) {
        uint2 ua, ub;
        ua.x = cvtpk(oA[c][0] * ivA, oA[c][1] * ivA);
        ua.y = cvtpk(oA[c][2] * ivA, oA[c][3] * ivA);
        ub.x = cvtpk(oB[c][0] * ivB, oB[c][1] * ivB);
        ub.y = cvtpk(oB[c][2] * ivB, oB[c][3] * ivB);
        int col = h * 64 + c * 16 + lg * 4;
        *(uint2*)&Ob[((size_t)b * S_ + qA + lr) * D_ + col] = ua;
        *(uint2*)&Ob[((size_t)b * S_ + qB + lr) * D_ + col] = ub;
    }
}

// ---------------- out-proj GEMM: [8192,1024] x [1024,1024] + bias, f32 out ----------------
__launch_bounds__(256)
__global__ void k_gemm_proj(const unsigned short* __restrict__ A,
                            const unsigned short* __restrict__ Bt,
                            const float* __restrict__ bias,
                            float* __restrict__ out) {
    __shared__ unsigned short Al[128 * GBK];
    __shared__ unsigned short Bl[128 * GBK];
    const int m0 = blockIdx.y * 128;
    const int n0 = blockIdx.x * 128;
    const int t = threadIdx.x;
    const int w = t >> 6, l = t & 63;
    const int wr = w >> 1, wc = w & 1;
    const int lr = l & 15, lg = l >> 4;
    const int srow = w * 32 + (l >> 3);
    const int scol = (l & 7) * 8;
    fx4 acc[4][4] = {};

    for (int k0 = 0; k0 < D_; k0 += GBK) {
        __syncthreads();
#pragma unroll
        for (int j = 0; j < 4; ++j) {
            gll16(&A [(size_t)(m0 + srow + j * 8) * D_ + k0 + scol], &Al[(w * 32 + j * 8) * GBK]);
            gll16(&Bt[(size_t)(n0 + srow + j * 8) * D_ + k0 + scol], &Bl[(w * 32 + j * 8) * GBK]);
        }
        __syncthreads();
#pragma unroll
        for (int kk = 0; kk < 2; ++kk) {
            bfx8 af[4], bf[4];
#pragma unroll
            for (int i = 0; i < 4; ++i) af[i] = *(const bfx8*)&Al[(wr * 64 + i * 16 + lr) * GBK + kk * 32 + lg * 8];
#pragma unroll
            for (int i = 0; i < 4; ++i) bf[i] = *(const bfx8*)&Bl[(wc * 64 + i * 16 + lr) * GBK + kk * 32 + lg * 8];
#pragma unroll
            for (int mi = 0; mi < 4; ++mi)
#pragma unroll
                for (int ni = 0; ni < 4; ++ni)
                    acc[mi][ni] = __builtin_amdgcn_mfma_f32_16x16x32_bf16(af[mi], bf[ni], acc[mi][ni], 0, 0, 0);
        }
    }
#pragma unroll
    for (int ni = 0; ni < 4; ++ni) {
        int col = n0 + wc * 64 + ni * 16 + lr;
        float bv = bias[col];
#pragma unroll
        for (int mi = 0; mi < 4; ++mi)
#pragma unroll
            for (int i = 0; i < 4; ++i) {
                int m = m0 + wr * 64 + mi * 16 + lg * 4 + i;
                out[(size_t)m * D_ + col] = acc[mi][ni][i] + bv;
            }
    }
}

extern "C" void kernel_launch(void* const* d_in, const int* in_sizes, int n_in,
                              void* d_out, int out_size, void* d_ws, size_t ws_size,
                              hipStream_t stream) {
    const float* x     = (const float*)d_in[0];
    const float* w_qkv = (const float*)d_in[1];
    const float* b_qkv = (const float*)d_in[2];
    const float* w_out = (const float*)d_in[3];
    const float* b_out = (const float*)d_in[4];
    float* out = (float*)d_out;

    unsigned short* xb    = (unsigned short*)d_ws;          // 8192*1024
    unsigned short* wqkvT = xb    + (size_t)MTOK * D_;      // 3072*1024
    unsigned short* woutT = wqkvT + (size_t)3 * D_ * D_;    // 1024*1024
    unsigned short* Qw    = woutT + (size_t)D_ * D_;        // 8192*1024
    unsigned short* Kw    = Qw    + (size_t)MTOK * D_;
    unsigned short* Vt    = Kw    + (size_t)MTOK * D_;
    unsigned short* attnb = Vt    + (size_t)MTOK * D_;

    k_conv_x<<<2048, 256, 0, stream>>>(x, xb, MTOK * D_ / 8);
    k_transpose_bf<<<(3 * D_ * (D_ / 8)) / 256, 256, 0, stream>>>(w_qkv, wqkvT, D_, 3 * D_);
    k_transpose_bf<<<(D_ * (D_ / 8)) / 256, 256, 0, stream>>>(w_out, woutT, D_, D_);
    k_gemm_qkv<<<dim3(24, 64), 256, 0, stream>>>(xb, wqkvT, b_qkv, Qw, Kw, Vt);
    k_attn<<<dim3(8, B_ * H_), 512, 0, stream>>>(Qw, Kw, Vt, attnb);
    k_gemm_proj<<<dim3(8, 64), 256, 0, stream>>>(attnb, woutT, b_out, out);
}

// Round 5
// 213.082 us; speedup vs baseline: 2.9480x; 1.1074x over previous
//
#include <hip/hip_runtime.h>
#include <hip/hip_bf16.h>
#include <stdint.h>

// CausalSelfAttention: B=4 S=2048 D=1024 H=16 hd=64
// conv(x) -> QKV gemm (global_load_lds BK=32, swapped-mfma epilogue, packed stores)
//        -> V transpose (LDS-tiled) -> flash attn (swapped QK^T, lane-local softmax)
//        -> out-proj gemm (swapped, float4 stores)

#define B_   4
#define S_   2048
#define D_   1024
#define H_   16
#define HD_  64
#define MTOK (B_ * S_)   // 8192
#define BK   32
#define QSCALE 0.18033688011112042f   // 0.125 * log2(e)

typedef __attribute__((ext_vector_type(8))) short bfx8;
typedef __attribute__((ext_vector_type(4))) float fx4;

static __device__ __forceinline__ unsigned short f2bf(float f) {
    union { float f; uint32_t u; } v{f};
    uint32_t u = v.u;
    u += 0x7fffu + ((u >> 16) & 1u);   // RNE
    return (unsigned short)(u >> 16);
}

static __device__ __forceinline__ uint32_t cvtpk(float lo, float hi) {
    uint32_t r;
    asm volatile("v_cvt_pk_bf16_f32 %0, %1, %2" : "=v"(r) : "v"(lo), "v"(hi));
    return r;
}

// global -> LDS direct DMA, 16B/lane; LDS dest = wave-uniform base + lane*16
static __device__ __forceinline__ void gll16(const unsigned short* g, const unsigned short* l) {
    typedef const __attribute__((address_space(1))) void* gp_t;
    typedef __attribute__((address_space(3))) void* lp_t;
    __builtin_amdgcn_global_load_lds((gp_t)(uintptr_t)g, (lp_t)(uint32_t)(uintptr_t)l, 16, 0, 0);
}

// ---------------- convert x f32 -> bf16 ----------------
__global__ void k_conv_x(const float* __restrict__ x, unsigned short* __restrict__ xb, int n8) {
    int i = blockIdx.x * blockDim.x + threadIdx.x;
    int stride = gridDim.x * blockDim.x;
    for (; i < n8; i += stride) {
        const float4* p = (const float4*)(x + (size_t)i * 8);
        float4 a = p[0], b = p[1];
        bfx8 o;
        o[0]=f2bf(a.x); o[1]=f2bf(a.y); o[2]=f2bf(a.z); o[3]=f2bf(a.w);
        o[4]=f2bf(b.x); o[5]=f2bf(b.y); o[6]=f2bf(b.z); o[7]=f2bf(b.w);
        *(bfx8*)(xb + (size_t)i * 8) = o;
    }
}

// ---------------- transpose W [K][N] f32 -> Wt [N][K] bf16 ----------------
__global__ void k_transpose_bf(const float* __restrict__ w, unsigned short* __restrict__ wt,
                               int K, int N) {
    int idx = blockIdx.x * blockDim.x + threadIdx.x;
    int total = N * (K / 8);
    if (idx >= total) return;
    int n  = idx % N;
    int k0 = (idx / N) * 8;
    bfx8 o;
#pragma unroll
    for (int j = 0; j < 8; ++j) o[j] = f2bf(w[(size_t)(k0 + j) * N + n]);
    *(bfx8*)(wt + (size_t)n * K + k0) = o;
}

// ---------------- V transpose: Vw [bh][s][64] -> Vt [bh][64][s] ----------------
__global__ void k_transpose_v(const unsigned short* __restrict__ Vw,
                              unsigned short* __restrict__ Vt) {
    __shared__ unsigned short lds[64][72];
    const int bg = blockIdx.x;            // 2048 = 64 bh x 32 s-tiles
    const int bh = bg >> 5;
    const int st = (bg & 31) * 64;
    const int t = threadIdx.x;
#pragma unroll
    for (int j = 0; j < 2; ++j) {
        int c = t + 256 * j;
        int row = c >> 3, q = c & 7;
        *(bfx8*)&lds[row][q * 8] = *(const bfx8*)&Vw[((size_t)bh * S_ + st + row) * HD_ + q * 8];
    }
    __syncthreads();
#pragma unroll
    for (int j = 0; j < 2; ++j) {
        int c = t + 256 * j;
        int d = c >> 3, q = c & 7;
        bfx8 o;
#pragma unroll
        for (int e = 0; e < 8; ++e) o[e] = lds[q * 8 + e][d];
        *(bfx8*)&Vt[((size_t)bh * HD_ + d) * S_ + st + q * 8] = o;
    }
}

// ---------------- QKV GEMM: [8192,1024] x [1024,3072], BK=32, swapped mfma ----------------
__launch_bounds__(256)
__global__ void k_gemm_qkv(const unsigned short* __restrict__ A,
                           const unsigned short* __restrict__ Bt,
                           const float* __restrict__ bias,
                           unsigned short* __restrict__ Qw,
                           unsigned short* __restrict__ Kw,
                           unsigned short* __restrict__ Vw) {
    __shared__ unsigned short Al[128 * BK];   // 8KB, 64B rows
    __shared__ unsigned short Bl[128 * BK];
    // XCD swizzle: 1536 blocks -> contiguous 192-chunk per XCD, nx fast
    const int wg = blockIdx.x;
    const int lin = (wg & 7) * 192 + (wg >> 3);
    const int ny = lin / 24, nx = lin - ny * 24;
    const int m0 = ny * 128;
    const int n0 = nx * 128;
    const int t = threadIdx.x;
    const int w = t >> 6, l = t & 63;
    const int wr = w >> 1, wc = w & 1;
    const int lr = l & 15, lg = l >> 4;
    const int srow = l >> 2;                  // staging row within 16-row wave chunk
    const int scol = (l & 3) * 8;             // staging col (elems)
    fx4 acc[4][4] = {};

    for (int k0 = 0; k0 < D_; k0 += BK) {
        __syncthreads();
#pragma unroll
        for (int j = 0; j < 2; ++j) {         // 2 sweeps x (A+B): 16KB staged
            int rb = j * 64 + w * 16;
            gll16(&A [(size_t)(m0 + rb + srow) * D_ + k0 + scol], &Al[rb * BK]);
            gll16(&Bt[(size_t)(n0 + rb + srow) * D_ + k0 + scol], &Bl[rb * BK]);
        }
        __syncthreads();
        bfx8 af[4], bf[4];
#pragma unroll
        for (int i = 0; i < 4; ++i) af[i] = *(const bfx8*)&Al[(wr * 64 + i * 16 + lr) * BK + lg * 8];
#pragma unroll
        for (int i = 0; i < 4; ++i) bf[i] = *(const bfx8*)&Bl[(wc * 64 + i * 16 + lr) * BK + lg * 8];
#pragma unroll
        for (int mi = 0; mi < 4; ++mi)
#pragma unroll
            for (int ni = 0; ni < 4; ++ni)    // swapped: lane holds m=lr, n=lg*4+i
                acc[mi][ni] = __builtin_amdgcn_mfma_f32_16x16x32_bf16(bf[ni], af[mi], acc[mi][ni], 0, 0, 0);
    }

    // epilogue: lane has 4 consecutive n -> packed 8B stores
#pragma unroll
    for (int ni = 0; ni < 4; ++ni) {
        const int nn = n0 + wc * 64 + ni * 16 + lg * 4;   // 4 consecutive cols
        const int mat = nn >> 10;
        const int h = (nn & 1023) >> 6, dd = nn & 63;
        const float4 bv = *(const float4*)&bias[nn];
        unsigned short* dst = (mat == 0) ? Qw : (mat == 1) ? Kw : Vw;
        const float sc = (mat == 0) ? QSCALE : 1.0f;
#pragma unroll
        for (int mi = 0; mi < 4; ++mi) {
            const int m = m0 + wr * 64 + mi * 16 + lr;
            const int b = m >> 11, s = m & 2047;
            const int bh = b * H_ + h;
            fx4 v = acc[mi][ni];
            float o0 = (v[0] + bv.x) * sc, o1 = (v[1] + bv.y) * sc;
            float o2 = (v[2] + bv.z) * sc, o3 = (v[3] + bv.w) * sc;
            uint2 u; u.x = cvtpk(o0, o1); u.y = cvtpk(o2, o3);
            *(uint2*)&dst[((size_t)bh * S_ + s) * HD_ + dd] = u;
        }
    }
}

// ---------------- flash attention (swapped QK^T, lane-local softmax) ----------------
// 8 waves, paired q-tiles (pi, 15-pi), kv tile 64, K/V LDS double-buffered + swizzled.
// XCD-grouped grid: all 8 pi of a bh land on one XCD -> K/V stays in its L2.
__launch_bounds__(512, 4)
__global__ void k_attn(const unsigned short* __restrict__ Qw,
                       const unsigned short* __restrict__ Kw,
                       const unsigned short* __restrict__ Vt,
                       unsigned short* __restrict__ Ob) {
    __shared__ unsigned short Kl[2][64 * 64];   // [kv][d], row=128B, XOR-swizzled
    __shared__ unsigned short Vl[2][64 * 64];   // [d][kv], row=128B, XOR-swizzled
    __shared__ unsigned short Pl[8][16 * 72];   // per-wave P [q][kv], stride 72 elems
    const int wg = blockIdx.x;                  // 512
    const int xcd = wg & 7, ix = wg >> 3;       // ix 0..63
    const int bh = xcd * 8 + (ix >> 3);
    const int pi = ix & 7;
    const int t = threadIdx.x;
    const int w = t >> 6, l = t & 63;
    const int lr = l & 15, lg = l >> 4;
    const int qA = pi * 128 + w * 16;
    const int qB = (15 - pi) * 128 + w * 16;
    const int NT = 32 - 2 * pi;

    const unsigned short* Qp = Qw + (size_t)bh * S_ * HD_;
    const unsigned short* Kp = Kw + (size_t)bh * S_ * HD_;
    const unsigned short* Vp = Vt + (size_t)bh * HD_ * S_;

    bfx8 qfA[2], qfB[2];
#pragma unroll
    for (int kk = 0; kk < 2; ++kk) {
        qfA[kk] = *(const bfx8*)&Qp[(size_t)(qA + lr) * HD_ + kk * 32 + lg * 8];
        qfB[kk] = *(const bfx8*)&Qp[(size_t)(qB + lr) * HD_ + kk * 32 + lg * 8];
    }

    fx4 oA[4] = {}, oB[4] = {};
    float mA = -1e30f, lA = 0.f, mB = -1e30f, lB = 0.f;

    auto compute = [&](int qr, const bfx8* qf, fx4* oacc, float& mrow, float& lsum,
                       int kv0, int buf) {
        fx4 sacc[4] = {};
#pragma unroll
        for (int c = 0; c < 4; ++c) {
            int row = c * 16 + lr;
#pragma unroll
            for (int kk = 0; kk < 2; ++kk) {
                int colb = kk * 64 + lg * 16;
                bfx8 kf = *(const bfx8*)((const char*)&Kl[buf][0] + row * 128 + (colb ^ ((row & 7) << 4)));
                sacc[c] = __builtin_amdgcn_mfma_f32_16x16x32_bf16(kf, qf[kk], sacc[c], 0, 0, 0);
            }
        }
        if (kv0 + 63 > qr) {
            const int qrel = qr + lr - kv0;
#pragma unroll
            for (int c = 0; c < 4; ++c)
#pragma unroll
                for (int i = 0; i < 4; ++i)
                    if (c * 16 + lg * 4 + i > qrel) sacc[c][i] = -1e30f;
        }
        float mc0 = fmaxf(fmaxf(sacc[0][0], sacc[0][1]), fmaxf(sacc[0][2], sacc[0][3]));
        float mc1 = fmaxf(fmaxf(sacc[1][0], sacc[1][1]), fmaxf(sacc[1][2], sacc[1][3]));
        float mc2 = fmaxf(fmaxf(sacc[2][0], sacc[2][1]), fmaxf(sacc[2][2], sacc[2][3]));
        float mc3 = fmaxf(fmaxf(sacc[3][0], sacc[3][1]), fmaxf(sacc[3][2], sacc[3][3]));
        float mx = fmaxf(fmaxf(mc0, mc1), fmaxf(mc2, mc3));
        mx = fmaxf(mx, __shfl_xor(mx, 16));
        mx = fmaxf(mx, __shfl_xor(mx, 32));
        float mnew = fmaxf(mrow, mx);
        float al = exp2f(mrow - mnew);
        mrow = mnew;
        float ps = 0.f;
        uint32_t pk[4][2];
#pragma unroll
        for (int c = 0; c < 4; ++c)
#pragma unroll
            for (int r = 0; r < 2; ++r) {
                float p0 = exp2f(sacc[c][2 * r]     - mnew);
                float p1 = exp2f(sacc[c][2 * r + 1] - mnew);
                ps += p0 + p1;
                pk[c][r] = cvtpk(p0, p1);
            }
        ps += __shfl_xor(ps, 16);
        ps += __shfl_xor(ps, 32);
        lsum = lsum * al + ps;
#pragma unroll
        for (int c = 0; c < 4; ++c) {
            uint2 u; u.x = pk[c][0]; u.y = pk[c][1];
            *(uint2*)&Pl[w][lr * 72 + c * 16 + lg * 4] = u;
        }
#pragma unroll
        for (int c = 0; c < 4; ++c)
#pragma unroll
            for (int i = 0; i < 4; ++i) oacc[c][i] *= al;
#pragma unroll
        for (int kk = 0; kk < 2; ++kk) {
            bfx8 pf = *(const bfx8*)&Pl[w][lr * 72 + kk * 32 + lg * 8];
#pragma unroll
            for (int c = 0; c < 4; ++c) {
                int vrow = c * 16 + lr;
                int vcolb = kk * 64 + lg * 16;
                bfx8 vf = *(const bfx8*)((const char*)&Vl[buf][0] + vrow * 128 + (vcolb ^ ((vrow & 7) << 4)));
                oacc[c] = __builtin_amdgcn_mfma_f32_16x16x32_bf16(vf, pf, oacc[c], 0, 0, 0);
            }
        }
    };

    // ---- prologue: stage tile 0 into buf 0 ----
    {
        bfx8 sreg[2];
#pragma unroll
        for (int it = 0; it < 2; ++it) {
            int id = t + 512 * it;
            int c = id & 511;
            int row = c >> 3, q = c & 7;
            if (id < 512) sreg[it] = *(const bfx8*)&Kp[(size_t)row * HD_ + q * 8];
            else          sreg[it] = *(const bfx8*)&Vp[(size_t)row * S_ + q * 8];
        }
#pragma unroll
        for (int it = 0; it < 2; ++it) {
            int id = t + 512 * it;
            int c = id & 511;
            int row = c >> 3, q = c & 7;
            int off = row * 128 + ((q * 16) ^ ((row & 7) << 4));
            char* base = (id < 512) ? (char*)&Kl[0][0] : (char*)&Vl[0][0];
            *(bfx8*)(base + off) = sreg[it];
        }
    }
    __syncthreads();

    int buf = 0;
    for (int tkv = 0; tkv < NT; ++tkv) {
        const int kv0 = tkv * 64;
        const bool pre = (tkv + 1 < NT);
        bfx8 sreg[2];
        if (pre) {
            const int kn = kv0 + 64;
#pragma unroll
            for (int it = 0; it < 2; ++it) {
                int id = t + 512 * it;
                int c = id & 511;
                int row = c >> 3, q = c & 7;
                if (id < 512) sreg[it] = *(const bfx8*)&Kp[(size_t)(kn + row) * HD_ + q * 8];
                else          sreg[it] = *(const bfx8*)&Vp[(size_t)row * S_ + kn + q * 8];
            }
        }
        if (kv0 <= qB + 15) compute(qB, qfB, oB, mB, lB, kv0, buf);
        if (kv0 <= qA + 15) compute(qA, qfA, oA, mA, lA, kv0, buf);
        if (pre) {
#pragma unroll
            for (int it = 0; it < 2; ++it) {
                int id = t + 512 * it;
                int c = id & 511;
                int row = c >> 3, q = c & 7;
                int off = row * 128 + ((q * 16) ^ ((row & 7) << 4));
                char* base = (id < 512) ? (char*)&Kl[buf ^ 1][0] : (char*)&Vl[buf ^ 1][0];
                *(bfx8*)(base + off) = sreg[it];
            }
        }
        __syncthreads();
        buf ^= 1;
    }

    const int b = bh >> 4, h = bh & 15;
    const float ivA = __builtin_amdgcn_rcpf(lA);
    const float ivB = __builtin_amdgcn_rcpf(lB);
#pragma unroll
    for (int c = 0; c < 4; ++c) {
        uint2 ua, ub;
        ua.x = cvtpk(oA[c][0] * ivA, oA[c][1] * ivA);
        ua.y = cvtpk(oA[c][2] * ivA, oA[c][3] * ivA);
        ub.x = cvtpk(oB[c][0] * ivB, oB[c][1] * ivB);
        ub.y = cvtpk(oB[c][2] * ivB, oB[c][3] * ivB);
        int col = h * 64 + c * 16 + lg * 4;
        *(uint2*)&Ob[((size_t)b * S_ + qA + lr) * D_ + col] = ua;
        *(uint2*)&Ob[((size_t)b * S_ + qB + lr) * D_ + col] = ub;
    }
}

// ---------------- out-proj GEMM: [8192,1024] x [1024,1024] + bias, f32 out ----------------
__launch_bounds__(256)
__global__ void k_gemm_proj(const unsigned short* __restrict__ A,
                            const unsigned short* __restrict__ Bt,
                            const float* __restrict__ bias,
                            float* __restrict__ out) {
    __shared__ unsigned short Al[128 * BK];
    __shared__ unsigned short Bl[128 * BK];
    const int wg = blockIdx.x;                 // 512 blocks: 8 n x 64 m
    const int lin = (wg & 7) * 64 + (wg >> 3);
    const int ny = lin >> 3, nx = lin & 7;
    const int m0 = ny * 128;
    const int n0 = nx * 128;
    const int t = threadIdx.x;
    const int w = t >> 6, l = t & 63;
    const int wr = w >> 1, wc = w & 1;
    const int lr = l & 15, lg = l >> 4;
    const int srow = l >> 2;
    const int scol = (l & 3) * 8;
    fx4 acc[4][4] = {};

    for (int k0 = 0; k0 < D_; k0 += BK) {
        __syncthreads();
#pragma unroll
        for (int j = 0; j < 2; ++j) {
            int rb = j * 64 + w * 16;
            gll16(&A [(size_t)(m0 + rb + srow) * D_ + k0 + scol], &Al[rb * BK]);
            gll16(&Bt[(size_t)(n0 + rb + srow) * D_ + k0 + scol], &Bl[rb * BK]);
        }
        __syncthreads();
        bfx8 af[4], bf[4];
#pragma unroll
        for (int i = 0; i < 4; ++i) af[i] = *(const bfx8*)&Al[(wr * 64 + i * 16 + lr) * BK + lg * 8];
#pragma unroll
        for (int i = 0; i < 4; ++i) bf[i] = *(const bfx8*)&Bl[(wc * 64 + i * 16 + lr) * BK + lg * 8];
#pragma unroll
        for (int mi = 0; mi < 4; ++mi)
#pragma unroll
            for (int ni = 0; ni < 4; ++ni)
                acc[mi][ni] = __builtin_amdgcn_mfma_f32_16x16x32_bf16(bf[ni], af[mi], acc[mi][ni], 0, 0, 0);
    }
#pragma unroll
    for (int ni = 0; ni < 4; ++ni) {
        const int nn = n0 + wc * 64 + ni * 16 + lg * 4;
        const float4 bv = *(const float4*)&bias[nn];
#pragma unroll
        for (int mi = 0; mi < 4; ++mi) {
            const int m = m0 + wr * 64 + mi * 16 + lr;
            fx4 v = acc[mi][ni];
            float4 o; o.x = v[0] + bv.x; o.y = v[1] + bv.y; o.z = v[2] + bv.z; o.w = v[3] + bv.w;
            *(float4*)&out[(size_t)m * D_ + nn] = o;
        }
    }
}

extern "C" void kernel_launch(void* const* d_in, const int* in_sizes, int n_in,
                              void* d_out, int out_size, void* d_ws, size_t ws_size,
                              hipStream_t stream) {
    const float* x     = (const float*)d_in[0];
    const float* w_qkv = (const float*)d_in[1];
    const float* b_qkv = (const float*)d_in[2];
    const float* w_out = (const float*)d_in[3];
    const float* b_out = (const float*)d_in[4];
    float* out = (float*)d_out;

    unsigned short* xb    = (unsigned short*)d_ws;          // 8192*1024 (reused as Vt after qkv)
    unsigned short* wqkvT = xb    + (size_t)MTOK * D_;      // 3072*1024
    unsigned short* woutT = wqkvT + (size_t)3 * D_ * D_;    // 1024*1024
    unsigned short* Qw    = woutT + (size_t)D_ * D_;        // 8192*1024
    unsigned short* Kw    = Qw    + (size_t)MTOK * D_;
    unsigned short* Vw    = Kw    + (size_t)MTOK * D_;
    unsigned short* attnb = Vw    + (size_t)MTOK * D_;
    unsigned short* Vt    = xb;   // alias: xb is dead after k_gemm_qkv

    k_conv_x<<<2048, 256, 0, stream>>>(x, xb, MTOK * D_ / 8);
    k_transpose_bf<<<(3 * D_ * (D_ / 8)) / 256, 256, 0, stream>>>(w_qkv, wqkvT, D_, 3 * D_);
    k_transpose_bf<<<(D_ * (D_ / 8)) / 256, 256, 0, stream>>>(w_out, woutT, D_, D_);
    k_gemm_qkv<<<1536, 256, 0, stream>>>(xb, wqkvT, b_qkv, Qw, Kw, Vw);
    k_transpose_v<<<2048, 256, 0, stream>>>(Vw, Vt);
    k_attn<<<512, 512, 0, stream>>>(Qw, Kw, Vt, attnb);
    k_gemm_proj<<<512, 256, 0, stream>>>(attnb, woutT, b_out, out);
}

// Round 6
// 206.865 us; speedup vs baseline: 3.0366x; 1.0301x over previous
//
#include <hip/hip_runtime.h>
#include <hip/hip_bf16.h>
#include <stdint.h>

// CausalSelfAttention: B=4 S=2048 D=1024 H=16 hd=64
// conv(x) -> QKV gemm (global_load_lds BK=32, swapped-mfma epilogue, packed stores)
//        -> V transpose (LDS-tiled) -> flash attn (swapped QK^T, lane-local softmax,
//           ones-row lsum MFMA, defer-max, swizzled P, setprio)
//        -> out-proj gemm (swapped, float4 stores)

#define B_   4
#define S_   2048
#define D_   1024
#define H_   16
#define HD_  64
#define MTOK (B_ * S_)   // 8192
#define BK   32
#define QSCALE 0.18033688011112042f   // 0.125 * log2(e)

typedef __attribute__((ext_vector_type(8))) short bfx8;
typedef __attribute__((ext_vector_type(4))) float fx4;

static __device__ __forceinline__ unsigned short f2bf(float f) {
    union { float f; uint32_t u; } v{f};
    uint32_t u = v.u;
    u += 0x7fffu + ((u >> 16) & 1u);   // RNE
    return (unsigned short)(u >> 16);
}

static __device__ __forceinline__ uint32_t cvtpk(float lo, float hi) {
    uint32_t r;
    asm volatile("v_cvt_pk_bf16_f32 %0, %1, %2" : "=v"(r) : "v"(lo), "v"(hi));
    return r;
}

// global -> LDS direct DMA, 16B/lane; LDS dest = wave-uniform base + lane*16
static __device__ __forceinline__ void gll16(const unsigned short* g, const unsigned short* l) {
    typedef const __attribute__((address_space(1))) void* gp_t;
    typedef __attribute__((address_space(3))) void* lp_t;
    __builtin_amdgcn_global_load_lds((gp_t)(uintptr_t)g, (lp_t)(uint32_t)(uintptr_t)l, 16, 0, 0);
}

// ---------------- convert x f32 -> bf16 ----------------
__global__ void k_conv_x(const float* __restrict__ x, unsigned short* __restrict__ xb, int n8) {
    int i = blockIdx.x * blockDim.x + threadIdx.x;
    int stride = gridDim.x * blockDim.x;
    for (; i < n8; i += stride) {
        const float4* p = (const float4*)(x + (size_t)i * 8);
        float4 a = p[0], b = p[1];
        bfx8 o;
        o[0]=f2bf(a.x); o[1]=f2bf(a.y); o[2]=f2bf(a.z); o[3]=f2bf(a.w);
        o[4]=f2bf(b.x); o[5]=f2bf(b.y); o[6]=f2bf(b.z); o[7]=f2bf(b.w);
        *(bfx8*)(xb + (size_t)i * 8) = o;
    }
}

// ---------------- transpose W [K][N] f32 -> Wt [N][K] bf16 ----------------
__global__ void k_transpose_bf(const float* __restrict__ w, unsigned short* __restrict__ wt,
                               int K, int N) {
    int idx = blockIdx.x * blockDim.x + threadIdx.x;
    int total = N * (K / 8);
    if (idx >= total) return;
    int n  = idx % N;
    int k0 = (idx / N) * 8;
    bfx8 o;
#pragma unroll
    for (int j = 0; j < 8; ++j) o[j] = f2bf(w[(size_t)(k0 + j) * N + n]);
    *(bfx8*)(wt + (size_t)n * K + k0) = o;
}

// ---------------- V transpose: Vw [bh][s][64] -> Vt [bh][64][s] ----------------
__global__ void k_transpose_v(const unsigned short* __restrict__ Vw,
                              unsigned short* __restrict__ Vt) {
    __shared__ unsigned short lds[64][72];
    const int bg = blockIdx.x;            // 2048 = 64 bh x 32 s-tiles
    const int bh = bg >> 5;
    const int st = (bg & 31) * 64;
    const int t = threadIdx.x;
#pragma unroll
    for (int j = 0; j < 2; ++j) {
        int c = t + 256 * j;
        int row = c >> 3, q = c & 7;
        *(bfx8*)&lds[row][q * 8] = *(const bfx8*)&Vw[((size_t)bh * S_ + st + row) * HD_ + q * 8];
    }
    __syncthreads();
#pragma unroll
    for (int j = 0; j < 2; ++j) {
        int c = t + 256 * j;
        int d = c >> 3, q = c & 7;
        bfx8 o;
#pragma unroll
        for (int e = 0; e < 8; ++e) o[e] = lds[q * 8 + e][d];
        *(bfx8*)&Vt[((size_t)bh * HD_ + d) * S_ + st + q * 8] = o;
    }
}

// ---------------- QKV GEMM: [8192,1024] x [1024,3072], BK=32, swapped mfma ----------------
__launch_bounds__(256)
__global__ void k_gemm_qkv(const unsigned short* __restrict__ A,
                           const unsigned short* __restrict__ Bt,
                           const float* __restrict__ bias,
                           unsigned short* __restrict__ Qw,
                           unsigned short* __restrict__ Kw,
                           unsigned short* __restrict__ Vw) {
    __shared__ unsigned short Al[128 * BK];   // 8KB, 64B rows
    __shared__ unsigned short Bl[128 * BK];
    const int wg = blockIdx.x;
    const int lin = (wg & 7) * 192 + (wg >> 3);
    const int ny = lin / 24, nx = lin - ny * 24;
    const int m0 = ny * 128;
    const int n0 = nx * 128;
    const int t = threadIdx.x;
    const int w = t >> 6, l = t & 63;
    const int wr = w >> 1, wc = w & 1;
    const int lr = l & 15, lg = l >> 4;
    const int srow = l >> 2;
    const int scol = (l & 3) * 8;
    fx4 acc[4][4] = {};

    for (int k0 = 0; k0 < D_; k0 += BK) {
        __syncthreads();
#pragma unroll
        for (int j = 0; j < 2; ++j) {
            int rb = j * 64 + w * 16;
            gll16(&A [(size_t)(m0 + rb + srow) * D_ + k0 + scol], &Al[rb * BK]);
            gll16(&Bt[(size_t)(n0 + rb + srow) * D_ + k0 + scol], &Bl[rb * BK]);
        }
        __syncthreads();
        bfx8 af[4], bf[4];
#pragma unroll
        for (int i = 0; i < 4; ++i) af[i] = *(const bfx8*)&Al[(wr * 64 + i * 16 + lr) * BK + lg * 8];
#pragma unroll
        for (int i = 0; i < 4; ++i) bf[i] = *(const bfx8*)&Bl[(wc * 64 + i * 16 + lr) * BK + lg * 8];
#pragma unroll
        for (int mi = 0; mi < 4; ++mi)
#pragma unroll
            for (int ni = 0; ni < 4; ++ni)
                acc[mi][ni] = __builtin_amdgcn_mfma_f32_16x16x32_bf16(bf[ni], af[mi], acc[mi][ni], 0, 0, 0);
    }

#pragma unroll
    for (int ni = 0; ni < 4; ++ni) {
        const int nn = n0 + wc * 64 + ni * 16 + lg * 4;
        const int mat = nn >> 10;
        const int h = (nn & 1023) >> 6, dd = nn & 63;
        const float4 bv = *(const float4*)&bias[nn];
        unsigned short* dst = (mat == 0) ? Qw : (mat == 1) ? Kw : Vw;
        const float sc = (mat == 0) ? QSCALE : 1.0f;
#pragma unroll
        for (int mi = 0; mi < 4; ++mi) {
            const int m = m0 + wr * 64 + mi * 16 + lr;
            const int b = m >> 11, s = m & 2047;
            const int bh = b * H_ + h;
            fx4 v = acc[mi][ni];
            float o0 = (v[0] + bv.x) * sc, o1 = (v[1] + bv.y) * sc;
            float o2 = (v[2] + bv.z) * sc, o3 = (v[3] + bv.w) * sc;
            uint2 u; u.x = cvtpk(o0, o1); u.y = cvtpk(o2, o3);
            *(uint2*)&dst[((size_t)bh * S_ + s) * HD_ + dd] = u;
        }
    }
}

// ---------------- flash attention (swapped QK^T, lane-local softmax) ----------------
// 8 waves, paired q-tiles (pi, 15-pi), kv tile 64, K/V LDS double-buffered + swizzled.
// lsum via ones-row MFMA; defer-max (THR=8 base-2); Pl XOR-swizzled; setprio on MFMA.
__launch_bounds__(512, 4)
__global__ void k_attn(const unsigned short* __restrict__ Qw,
                       const unsigned short* __restrict__ Kw,
                       const unsigned short* __restrict__ Vt,
                       unsigned short* __restrict__ Ob) {
    __shared__ unsigned short Kl[2][64 * 64];   // [kv][d], row=128B, XOR-swizzled
    __shared__ unsigned short Vl[2][64 * 64];   // [d][kv], row=128B, XOR-swizzled
    __shared__ unsigned short Pl[8][16 * 64];   // per-wave P [q][kv], row=128B, XOR-swizzled
    const int wg = blockIdx.x;                  // 512
    const int xcd = wg & 7, ix = wg >> 3;
    const int bh = xcd * 8 + (ix >> 3);
    const int pi = ix & 7;
    const int t = threadIdx.x;
    const int w = t >> 6, l = t & 63;
    const int lr = l & 15, lg = l >> 4;
    const int qA = pi * 128 + w * 16;
    const int qB = (15 - pi) * 128 + w * 16;
    const int NT = 32 - 2 * pi;

    const unsigned short* Qp = Qw + (size_t)bh * S_ * HD_;
    const unsigned short* Kp = Kw + (size_t)bh * S_ * HD_;
    const unsigned short* Vp = Vt + (size_t)bh * HD_ * S_;

    bfx8 qfA[2], qfB[2];
#pragma unroll
    for (int kk = 0; kk < 2; ++kk) {
        qfA[kk] = *(const bfx8*)&Qp[(size_t)(qA + lr) * HD_ + kk * 32 + lg * 8];
        qfB[kk] = *(const bfx8*)&Qp[(size_t)(qB + lr) * HD_ + kk * 32 + lg * 8];
    }

    bfx8 ones;
#pragma unroll
    for (int j = 0; j < 8; ++j) ones[j] = (short)0x3F80;   // bf16 1.0

    fx4 oA[4] = {}, oB[4] = {};
    fx4 sA = {}, sB = {};                       // lsum accumulators (component 0 used)
    float mA = -1e30f, mB = -1e30f;

    auto compute = [&](int qr, const bfx8* qf, fx4* oacc, fx4& osum, float& mrow,
                       int kv0, int buf) {
        // S^T = K . Q^T
        fx4 sacc[4] = {};
        __builtin_amdgcn_s_setprio(1);
#pragma unroll
        for (int c = 0; c < 4; ++c) {
            int row = c * 16 + lr;
#pragma unroll
            for (int kk = 0; kk < 2; ++kk) {
                int colb = kk * 64 + lg * 16;
                bfx8 kf = *(const bfx8*)((const char*)&Kl[buf][0] + row * 128 + (colb ^ ((row & 7) << 4)));
                sacc[c] = __builtin_amdgcn_mfma_f32_16x16x32_bf16(kf, qf[kk], sacc[c], 0, 0, 0);
            }
        }
        __builtin_amdgcn_s_setprio(0);
        // causal mask: lane's q-row = qr+lr; kv = kv0 + 16c + lg*4 + i
        if (kv0 + 63 > qr) {
            const int qrel = qr + lr - kv0;
#pragma unroll
            for (int c = 0; c < 4; ++c)
#pragma unroll
                for (int i = 0; i < 4; ++i)
                    if (c * 16 + lg * 4 + i > qrel) sacc[c][i] = -1e30f;
        }
        // row max (lane-local 15 + 2 shuffles)
        float mc0 = fmaxf(fmaxf(sacc[0][0], sacc[0][1]), fmaxf(sacc[0][2], sacc[0][3]));
        float mc1 = fmaxf(fmaxf(sacc[1][0], sacc[1][1]), fmaxf(sacc[1][2], sacc[1][3]));
        float mc2 = fmaxf(fmaxf(sacc[2][0], sacc[2][1]), fmaxf(sacc[2][2], sacc[2][3]));
        float mc3 = fmaxf(fmaxf(sacc[3][0], sacc[3][1]), fmaxf(sacc[3][2], sacc[3][3]));
        float mx = fmaxf(fmaxf(mc0, mc1), fmaxf(mc2, mc3));
        mx = fmaxf(mx, __shfl_xor(mx, 16));
        mx = fmaxf(mx, __shfl_xor(mx, 32));
        // defer-max: rescale only when max grew beyond THR=8 (P bounded by 2^8)
        if (!__all(mx <= mrow + 8.f)) {
            float mnew = fmaxf(mrow, mx);
            float al = exp2f(mrow - mnew);
            mrow = mnew;
#pragma unroll
            for (int c = 0; c < 4; ++c)
#pragma unroll
                for (int i = 0; i < 4; ++i) oacc[c][i] *= al;
            osum[0] *= al;
        }
        // P = exp2(S-m) packed to bf16, stored swizzled
#pragma unroll
        for (int c = 0; c < 4; ++c) {
            float p0 = exp2f(sacc[c][0] - mrow);
            float p1 = exp2f(sacc[c][1] - mrow);
            float p2 = exp2f(sacc[c][2] - mrow);
            float p3 = exp2f(sacc[c][3] - mrow);
            uint2 u; u.x = cvtpk(p0, p1); u.y = cvtpk(p2, p3);
            *(uint2*)((char*)&Pl[w][0] + lr * 128 + ((c * 32 + lg * 8) ^ ((lr & 7) << 4))) = u;
        }
        // O^T += V^T . P^T ; lsum via ones-row MFMA
        __builtin_amdgcn_s_setprio(1);
#pragma unroll
        for (int kk = 0; kk < 2; ++kk) {
            bfx8 pf = *(const bfx8*)((const char*)&Pl[w][0] + lr * 128 + ((kk * 64 + lg * 16) ^ ((lr & 7) << 4)));
            osum = __builtin_amdgcn_mfma_f32_16x16x32_bf16(ones, pf, osum, 0, 0, 0);
#pragma unroll
            for (int c = 0; c < 4; ++c) {
                int vrow = c * 16 + lr;
                int vcolb = kk * 64 + lg * 16;
                bfx8 vf = *(const bfx8*)((const char*)&Vl[buf][0] + vrow * 128 + (vcolb ^ ((vrow & 7) << 4)));
                oacc[c] = __builtin_amdgcn_mfma_f32_16x16x32_bf16(vf, pf, oacc[c], 0, 0, 0);
            }
        }
        __builtin_amdgcn_s_setprio(0);
    };

    // ---- prologue: stage tile 0 into buf 0 ----
    {
        bfx8 sreg[2];
#pragma unroll
        for (int it = 0; it < 2; ++it) {
            int id = t + 512 * it;
            int c = id & 511;
            int row = c >> 3, q = c & 7;
            if (id < 512) sreg[it] = *(const bfx8*)&Kp[(size_t)row * HD_ + q * 8];
            else          sreg[it] = *(const bfx8*)&Vp[(size_t)row * S_ + q * 8];
        }
#pragma unroll
        for (int it = 0; it < 2; ++it) {
            int id = t + 512 * it;
            int c = id & 511;
            int row = c >> 3, q = c & 7;
            int off = row * 128 + ((q * 16) ^ ((row & 7) << 4));
            char* base = (id < 512) ? (char*)&Kl[0][0] : (char*)&Vl[0][0];
            *(bfx8*)(base + off) = sreg[it];
        }
    }
    __syncthreads();

    int buf = 0;
    for (int tkv = 0; tkv < NT; ++tkv) {
        const int kv0 = tkv * 64;
        const bool pre = (tkv + 1 < NT);
        bfx8 sreg[2];
        if (pre) {
            const int kn = kv0 + 64;
#pragma unroll
            for (int it = 0; it < 2; ++it) {
                int id = t + 512 * it;
                int c = id & 511;
                int row = c >> 3, q = c & 7;
                if (id < 512) sreg[it] = *(const bfx8*)&Kp[(size_t)(kn + row) * HD_ + q * 8];
                else          sreg[it] = *(const bfx8*)&Vp[(size_t)row * S_ + kn + q * 8];
            }
        }
        if (kv0 <= qB + 15) compute(qB, qfB, oB, sB, mB, kv0, buf);
        if (kv0 <= qA + 15) compute(qA, qfA, oA, sA, mA, kv0, buf);
        if (pre) {
#pragma unroll
            for (int it = 0; it < 2; ++it) {
                int id = t + 512 * it;
                int c = id & 511;
                int row = c >> 3, q = c & 7;
                int off = row * 128 + ((q * 16) ^ ((row & 7) << 4));
                char* base = (id < 512) ? (char*)&Kl[buf ^ 1][0] : (char*)&Vl[buf ^ 1][0];
                *(bfx8*)(base + off) = sreg[it];
            }
        }
        __syncthreads();
        buf ^= 1;
    }

    const int b = bh >> 4, h = bh & 15;
    const float ivA = __builtin_amdgcn_rcpf(sA[0]);
    const float ivB = __builtin_amdgcn_rcpf(sB[0]);
#pragma unroll
    for (int c = 0; c < 4; ++c) {
        uint2 ua, ub;
        ua.x = cvtpk(oA[c][0] * ivA, oA[c][1] * ivA);
        ua.y = cvtpk(oA[c][2] * ivA, oA[c][3] * ivA);
        ub.x = cvtpk(oB[c][0] * ivB, oB[c][1] * ivB);
        ub.y = cvtpk(oB[c][2] * ivB, oB[c][3] * ivB);
        int col = h * 64 + c * 16 + lg * 4;
        *(uint2*)&Ob[((size_t)b * S_ + qA + lr) * D_ + col] = ua;
        *(uint2*)&Ob[((size_t)b * S_ + qB + lr) * D_ + col] = ub;
    }
}

// ---------------- out-proj GEMM: [8192,1024] x [1024,1024] + bias, f32 out ----------------
__launch_bounds__(256)
__global__ void k_gemm_proj(const unsigned short* __restrict__ A,
                            const unsigned short* __restrict__ Bt,
                            const float* __restrict__ bias,
                            float* __restrict__ out) {
    __shared__ unsigned short Al[128 * BK];
    __shared__ unsigned short Bl[128 * BK];
    const int wg = blockIdx.x;                 // 512 blocks: 8 n x 64 m
    const int lin = (wg & 7) * 64 + (wg >> 3);
    const int ny = lin >> 3, nx = lin & 7;
    const int m0 = ny * 128;
    const int n0 = nx * 128;
    const int t = threadIdx.x;
    const int w = t >> 6, l = t & 63;
    const int wr = w >> 1, wc = w & 1;
    const int lr = l & 15, lg = l >> 4;
    const int srow = l >> 2;
    const int scol = (l & 3) * 8;
    fx4 acc[4][4] = {};

    for (int k0 = 0; k0 < D_; k0 += BK) {
        __syncthreads();
#pragma unroll
        for (int j = 0; j < 2; ++j) {
            int rb = j * 64 + w * 16;
            gll16(&A [(size_t)(m0 + rb + srow) * D_ + k0 + scol], &Al[rb * BK]);
            gll16(&Bt[(size_t)(n0 + rb + srow) * D_ + k0 + scol], &Bl[rb * BK]);
        }
        __syncthreads();
        bfx8 af[4], bf[4];
#pragma unroll
        for (int i = 0; i < 4; ++i) af[i] = *(const bfx8*)&Al[(wr * 64 + i * 16 + lr) * BK + lg * 8];
#pragma unroll
        for (int i = 0; i < 4; ++i) bf[i] = *(const bfx8*)&Bl[(wc * 64 + i * 16 + lr) * BK + lg * 8];
#pragma unroll
        for (int mi = 0; mi < 4; ++mi)
#pragma unroll
            for (int ni = 0; ni < 4; ++ni)
                acc[mi][ni] = __builtin_amdgcn_mfma_f32_16x16x32_bf16(bf[ni], af[mi], acc[mi][ni], 0, 0, 0);
    }
#pragma unroll
    for (int ni = 0; ni < 4; ++ni) {
        const int nn = n0 + wc * 64 + ni * 16 + lg * 4;
        const float4 bv = *(const float4*)&bias[nn];
#pragma unroll
        for (int mi = 0; mi < 4; ++mi) {
            const int m = m0 + wr * 64 + mi * 16 + lr;
            fx4 v = acc[mi][ni];
            float4 o; o.x = v[0] + bv.x; o.y = v[1] + bv.y; o.z = v[2] + bv.z; o.w = v[3] + bv.w;
            *(float4*)&out[(size_t)m * D_ + nn] = o;
        }
    }
}

extern "C" void kernel_launch(void* const* d_in, const int* in_sizes, int n_in,
                              void* d_out, int out_size, void* d_ws, size_t ws_size,
                              hipStream_t stream) {
    const float* x     = (const float*)d_in[0];
    const float* w_qkv = (const float*)d_in[1];
    const float* b_qkv = (const float*)d_in[2];
    const float* w_out = (const float*)d_in[3];
    const float* b_out = (const float*)d_in[4];
    float* out = (float*)d_out;

    unsigned short* xb    = (unsigned short*)d_ws;          // 8192*1024 (reused as Vt after qkv)
    unsigned short* wqkvT = xb    + (size_t)MTOK * D_;      // 3072*1024
    unsigned short* woutT = wqkvT + (size_t)3 * D_ * D_;    // 1024*1024
    unsigned short* Qw    = woutT + (size_t)D_ * D_;        // 8192*1024
    unsigned short* Kw    = Qw    + (size_t)MTOK * D_;
    unsigned short* Vw    = Kw    + (size_t)MTOK * D_;
    unsigned short* attnb = Vw    + (size_t)MTOK * D_;
    unsigned short* Vt    = xb;   // alias: xb is dead after k_gemm_qkv

    k_conv_x<<<2048, 256, 0, stream>>>(x, xb, MTOK * D_ / 8);
    k_transpose_bf<<<(3 * D_ * (D_ / 8)) / 256, 256, 0, stream>>>(w_qkv, wqkvT, D_, 3 * D_);
    k_transpose_bf<<<(D_ * (D_ / 8)) / 256, 256, 0, stream>>>(w_out, woutT, D_, D_);
    k_gemm_qkv<<<1536, 256, 0, stream>>>(xb, wqkvT, b_qkv, Qw, Kw, Vw);
    k_transpose_v<<<2048, 256, 0, stream>>>(Vw, Vt);
    k_attn<<<512, 512, 0, stream>>>(Qw, Kw, Vt, attnb);
    k_gemm_proj<<<512, 256, 0, stream>>>(attnb, woutT, b_out, out);
}

// Round 7
// 204.298 us; speedup vs baseline: 3.0748x; 1.0126x over previous
//
#include <hip/hip_runtime.h>
#include <hip/hip_bf16.h>
#include <stdint.h>

// CausalSelfAttention: B=4 S=2048 D=1024 H=16 hd=64
// conv(x) -> QKV gemm (global_load_lds BK=32, swapped-mfma epilogue, packed stores)
//        -> V transpose (LDS-tiled) -> flash attn v3 (32x32 mfma, swapped QK^T,
//           in-register P via permlane32_swap, defer-max, setprio)
//        -> out-proj gemm (swapped, float4 stores)

#define B_   4
#define S_   2048
#define D_   1024
#define H_   16
#define HD_  64
#define MTOK (B_ * S_)   // 8192
#define BK   32
#define QSCALE 0.18033688011112042f   // 0.125 * log2(e)

typedef __attribute__((ext_vector_type(8))) short bfx8;
typedef __attribute__((ext_vector_type(4))) float fx4;
typedef __attribute__((ext_vector_type(16))) float fx16;

static __device__ __forceinline__ unsigned short f2bf(float f) {
    union { float f; uint32_t u; } v{f};
    uint32_t u = v.u;
    u += 0x7fffu + ((u >> 16) & 1u);   // RNE
    return (unsigned short)(u >> 16);
}

static __device__ __forceinline__ uint32_t cvtpk(float lo, float hi) {
    uint32_t r;
    asm volatile("v_cvt_pk_bf16_f32 %0, %1, %2" : "=v"(r) : "v"(lo), "v"(hi));
    return r;
}

// v_permlane32_swap_b32: a.hi-lanes <-> b.lo-lanes (both registers updated)
static __device__ __forceinline__ void pswap(uint32_t& a, uint32_t& b) {
    asm volatile("v_permlane32_swap_b32 %0, %1" : "+v"(a), "+v"(b));
}

// global -> LDS direct DMA, 16B/lane; LDS dest = wave-uniform base + lane*16
static __device__ __forceinline__ void gll16(const unsigned short* g, const unsigned short* l) {
    typedef const __attribute__((address_space(1))) void* gp_t;
    typedef __attribute__((address_space(3))) void* lp_t;
    __builtin_amdgcn_global_load_lds((gp_t)(uintptr_t)g, (lp_t)(uint32_t)(uintptr_t)l, 16, 0, 0);
}

// ---------------- convert x f32 -> bf16 ----------------
__global__ void k_conv_x(const float* __restrict__ x, unsigned short* __restrict__ xb, int n8) {
    int i = blockIdx.x * blockDim.x + threadIdx.x;
    int stride = gridDim.x * blockDim.x;
    for (; i < n8; i += stride) {
        const float4* p = (const float4*)(x + (size_t)i * 8);
        float4 a = p[0], b = p[1];
        bfx8 o;
        o[0]=f2bf(a.x); o[1]=f2bf(a.y); o[2]=f2bf(a.z); o[3]=f2bf(a.w);
        o[4]=f2bf(b.x); o[5]=f2bf(b.y); o[6]=f2bf(b.z); o[7]=f2bf(b.w);
        *(bfx8*)(xb + (size_t)i * 8) = o;
    }
}

// ---------------- transpose W [K][N] f32 -> Wt [N][K] bf16 ----------------
__global__ void k_transpose_bf(const float* __restrict__ w, unsigned short* __restrict__ wt,
                               int K, int N) {
    int idx = blockIdx.x * blockDim.x + threadIdx.x;
    int total = N * (K / 8);
    if (idx >= total) return;
    int n  = idx % N;
    int k0 = (idx / N) * 8;
    bfx8 o;
#pragma unroll
    for (int j = 0; j < 8; ++j) o[j] = f2bf(w[(size_t)(k0 + j) * N + n]);
    *(bfx8*)(wt + (size_t)n * K + k0) = o;
}

// ---------------- V transpose: Vw [bh][s][64] -> Vt [bh][64][s] ----------------
__global__ void k_transpose_v(const unsigned short* __restrict__ Vw,
                              unsigned short* __restrict__ Vt) {
    __shared__ unsigned short lds[64][72];
    const int bg = blockIdx.x;            // 2048 = 64 bh x 32 s-tiles
    const int bh = bg >> 5;
    const int st = (bg & 31) * 64;
    const int t = threadIdx.x;
#pragma unroll
    for (int j = 0; j < 2; ++j) {
        int c = t + 256 * j;
        int row = c >> 3, q = c & 7;
        *(bfx8*)&lds[row][q * 8] = *(const bfx8*)&Vw[((size_t)bh * S_ + st + row) * HD_ + q * 8];
    }
    __syncthreads();
#pragma unroll
    for (int j = 0; j < 2; ++j) {
        int c = t + 256 * j;
        int d = c >> 3, q = c & 7;
        bfx8 o;
#pragma unroll
        for (int e = 0; e < 8; ++e) o[e] = lds[q * 8 + e][d];
        *(bfx8*)&Vt[((size_t)bh * HD_ + d) * S_ + st + q * 8] = o;
    }
}

// ---------------- QKV GEMM: [8192,1024] x [1024,3072], BK=32, swapped mfma ----------------
__launch_bounds__(256)
__global__ void k_gemm_qkv(const unsigned short* __restrict__ A,
                           const unsigned short* __restrict__ Bt,
                           const float* __restrict__ bias,
                           unsigned short* __restrict__ Qw,
                           unsigned short* __restrict__ Kw,
                           unsigned short* __restrict__ Vw) {
    __shared__ unsigned short Al[128 * BK];   // 8KB, 64B rows
    __shared__ unsigned short Bl[128 * BK];
    const int wg = blockIdx.x;
    const int lin = (wg & 7) * 192 + (wg >> 3);
    const int ny = lin / 24, nx = lin - ny * 24;
    const int m0 = ny * 128;
    const int n0 = nx * 128;
    const int t = threadIdx.x;
    const int w = t >> 6, l = t & 63;
    const int wr = w >> 1, wc = w & 1;
    const int lr = l & 15, lg = l >> 4;
    const int srow = l >> 2;
    const int scol = (l & 3) * 8;
    fx4 acc[4][4] = {};

    for (int k0 = 0; k0 < D_; k0 += BK) {
        __syncthreads();
#pragma unroll
        for (int j = 0; j < 2; ++j) {
            int rb = j * 64 + w * 16;
            gll16(&A [(size_t)(m0 + rb + srow) * D_ + k0 + scol], &Al[rb * BK]);
            gll16(&Bt[(size_t)(n0 + rb + srow) * D_ + k0 + scol], &Bl[rb * BK]);
        }
        __syncthreads();
        bfx8 af[4], bf[4];
#pragma unroll
        for (int i = 0; i < 4; ++i) af[i] = *(const bfx8*)&Al[(wr * 64 + i * 16 + lr) * BK + lg * 8];
#pragma unroll
        for (int i = 0; i < 4; ++i) bf[i] = *(const bfx8*)&Bl[(wc * 64 + i * 16 + lr) * BK + lg * 8];
#pragma unroll
        for (int mi = 0; mi < 4; ++mi)
#pragma unroll
            for (int ni = 0; ni < 4; ++ni)
                acc[mi][ni] = __builtin_amdgcn_mfma_f32_16x16x32_bf16(bf[ni], af[mi], acc[mi][ni], 0, 0, 0);
    }

#pragma unroll
    for (int ni = 0; ni < 4; ++ni) {
        const int nn = n0 + wc * 64 + ni * 16 + lg * 4;
        const int mat = nn >> 10;
        const int h = (nn & 1023) >> 6, dd = nn & 63;
        const float4 bv = *(const float4*)&bias[nn];
        unsigned short* dst = (mat == 0) ? Qw : (mat == 1) ? Kw : Vw;
        const float sc = (mat == 0) ? QSCALE : 1.0f;
#pragma unroll
        for (int mi = 0; mi < 4; ++mi) {
            const int m = m0 + wr * 64 + mi * 16 + lr;
            const int b = m >> 11, s = m & 2047;
            const int bh = b * H_ + h;
            fx4 v = acc[mi][ni];
            float o0 = (v[0] + bv.x) * sc, o1 = (v[1] + bv.y) * sc;
            float o2 = (v[2] + bv.z) * sc, o3 = (v[3] + bv.w) * sc;
            uint2 u; u.x = cvtpk(o0, o1); u.y = cvtpk(o2, o3);
            *(uint2*)&dst[((size_t)bh * S_ + s) * HD_ + dd] = u;
        }
    }
}

// ---------------- flash attention v3 (32x32 mfma, in-register P) ----------------
// 8 waves: w0-3 = big tile (15-pi) rows, w4-7 = small tile (pi) rows; 32 q-rows/wave.
// S^T = mfma32(K, Q): lane q = qr + (l&31); kv = (r&3)+8(r>>2)+4(l>>5) per 32-block.
// P redistributed to PV B-frags purely via v_permlane32_swap_b32 (no LDS).
__launch_bounds__(512, 4)
__global__ void k_attn(const unsigned short* __restrict__ Qw,
                       const unsigned short* __restrict__ Kw,
                       const unsigned short* __restrict__ Vt,
                       unsigned short* __restrict__ Ob) {
    __shared__ unsigned short Kl[2][64 * 64];   // [kv][d], row=128B, XOR-swizzled
    __shared__ unsigned short Vl[2][64 * 64];   // [d][kv], row=128B, XOR-swizzled
    const int wg = blockIdx.x;                  // 512
    const int xcd = wg & 7, ix = wg >> 3;
    const int bh = xcd * 8 + (ix >> 3);
    const int pi = ix & 7;
    const int t = threadIdx.x;
    const int w = t >> 6, l = t & 63;
    const int lq = l & 31, hi = l >> 5;
    const int tile = (w < 4) ? (15 - pi) : pi;
    const int qr = tile * 128 + (w & 3) * 32;   // this wave's 32-row base
    const int NT = 32 - 2 * pi;

    const unsigned short* Qp = Qw + (size_t)bh * S_ * HD_;
    const unsigned short* Kp = Kw + (size_t)bh * S_ * HD_;
    const unsigned short* Vp = Vt + (size_t)bh * HD_ * S_;

    bfx8 qf[4];   // B-frag: col q = lq, k(d) = kb*16 + hi*8
#pragma unroll
    for (int kb = 0; kb < 4; ++kb)
        qf[kb] = *(const bfx8*)&Qp[(size_t)(qr + lq) * HD_ + kb * 16 + hi * 8];

    fx16 oacc[2] = {};
    float mrow = -1e30f, lsum = 0.f;

    // one PV k-slice: build P B-frag from 4 packed words via 2 permlane swaps, 2 mfma
    auto pvstep = [&](const uint32_t* pk, int s, int cb, int buf) {
        uint32_t w0 = pk[4 * s], w1 = pk[4 * s + 1], w2 = pk[4 * s + 2], w3 = pk[4 * s + 3];
        pswap(w0, w2);
        pswap(w1, w3);
        union { uint32_t u[4]; bfx8 v; } pf;
        pf.u[0] = w0; pf.u[1] = w1; pf.u[2] = w2; pf.u[3] = w3;
        bfx8 v0 = *(const bfx8*)((const char*)&Vl[buf][0] + lq * 128 + (cb ^ ((lq & 7) << 4)));
        bfx8 v1 = *(const bfx8*)((const char*)&Vl[buf][0] + (32 + lq) * 128 + (cb ^ ((lq & 7) << 4)));
        oacc[0] = __builtin_amdgcn_mfma_f32_32x32x16_bf16(v0, pf.v, oacc[0], 0, 0, 0);
        oacc[1] = __builtin_amdgcn_mfma_f32_32x32x16_bf16(v1, pf.v, oacc[1], 0, 0, 0);
    };

    // ---- prologue: stage tile 0 into buf 0 ----
    {
        bfx8 sreg[2];
#pragma unroll
        for (int it = 0; it < 2; ++it) {
            int id = t + 512 * it;
            int c = id & 511;
            int row = c >> 3, q = c & 7;
            if (id < 512) sreg[it] = *(const bfx8*)&Kp[(size_t)row * HD_ + q * 8];
            else          sreg[it] = *(const bfx8*)&Vp[(size_t)row * S_ + q * 8];
        }
#pragma unroll
        for (int it = 0; it < 2; ++it) {
            int id = t + 512 * it;
            int c = id & 511;
            int row = c >> 3, q = c & 7;
            int off = row * 128 + ((q * 16) ^ ((row & 7) << 4));
            char* base = (id < 512) ? (char*)&Kl[0][0] : (char*)&Vl[0][0];
            *(bfx8*)(base + off) = sreg[it];
        }
    }
    __syncthreads();

    int buf = 0;
    for (int tkv = 0; tkv < NT; ++tkv) {
        const int kv0 = tkv * 64;
        const bool pre = (tkv + 1 < NT);
        bfx8 sreg[2];
        if (pre) {
            const int kn = kv0 + 64;
#pragma unroll
            for (int it = 0; it < 2; ++it) {
                int id = t + 512 * it;
                int c = id & 511;
                int row = c >> 3, q = c & 7;
                if (id < 512) sreg[it] = *(const bfx8*)&Kp[(size_t)(kn + row) * HD_ + q * 8];
                else          sreg[it] = *(const bfx8*)&Vp[(size_t)row * S_ + kn + q * 8];
            }
        }
        if (kv0 <= qr + 31) {
            // --- S^T = K . Q^T: 8x mfma 32x32x16 ---
            fx16 s0 = {}, s1 = {};
            __builtin_amdgcn_s_setprio(1);
#pragma unroll
            for (int kb = 0; kb < 4; ++kb) {
                const int cb = kb * 32 + hi * 16;
                bfx8 k0 = *(const bfx8*)((const char*)&Kl[buf][0] + lq * 128 + (cb ^ ((lq & 7) << 4)));
                bfx8 k1 = *(const bfx8*)((const char*)&Kl[buf][0] + (32 + lq) * 128 + (cb ^ ((lq & 7) << 4)));
                s0 = __builtin_amdgcn_mfma_f32_32x32x16_bf16(k0, qf[kb], s0, 0, 0, 0);
                s1 = __builtin_amdgcn_mfma_f32_32x32x16_bf16(k1, qf[kb], s1, 0, 0, 0);
            }
            __builtin_amdgcn_s_setprio(0);
            // --- causal mask (kv0 <= qr always, so every lane keeps >=1 elem) ---
            if (kv0 + 63 > qr) {
                const int qrel = qr + lq - kv0;
#pragma unroll
                for (int r = 0; r < 16; ++r) {
                    const int kvo = (r & 3) + 8 * (r >> 2) + 4 * hi;
                    if (kvo > qrel)      s0[r] = -1e30f;
                    if (kvo + 32 > qrel) s1[r] = -1e30f;
                }
            }
            // --- row max: 31 local fmax + 1 partner swap ---
            float mx = fmaxf(s0[0], s1[0]);
#pragma unroll
            for (int r = 1; r < 16; ++r) mx = fmaxf(mx, fmaxf(s0[r], s1[r]));
            mx = fmaxf(mx, __shfl_xor(mx, 32));
            // --- defer-max rescale (THR=8, base-2) ---
            if (!__all(mx <= mrow + 8.f)) {
                const float mnew = fmaxf(mrow, mx);
                const float al = exp2f(mrow - mnew);
                mrow = mnew;
#pragma unroll
                for (int r = 0; r < 16; ++r) { oacc[0][r] *= al; oacc[1][r] *= al; }
                lsum *= al;
            }
            // --- P = exp2(S - m), pack to bf16 words ---
            uint32_t pk0[8], pk1[8];
            float ps = 0.f;
#pragma unroll
            for (int j = 0; j < 8; ++j) {
                float a0 = exp2f(s0[2 * j] - mrow), b0 = exp2f(s0[2 * j + 1] - mrow);
                float a1 = exp2f(s1[2 * j] - mrow), b1 = exp2f(s1[2 * j + 1] - mrow);
                ps += (a0 + b0) + (a1 + b1);
                pk0[j] = cvtpk(a0, b0);
                pk1[j] = cvtpk(a1, b1);
            }
            lsum += ps + __shfl_xor(ps, 32);
            // --- O^T += V^T . P^T: 4 k-slices x 2 d-blocks ---
            __builtin_amdgcn_s_setprio(1);
            pvstep(pk0, 0, 0 * 32 + hi * 16, buf);
            pvstep(pk0, 1, 1 * 32 + hi * 16, buf);
            pvstep(pk1, 0, 2 * 32 + hi * 16, buf);
            pvstep(pk1, 1, 3 * 32 + hi * 16, buf);
            __builtin_amdgcn_s_setprio(0);
        }
        if (pre) {
#pragma unroll
            for (int it = 0; it < 2; ++it) {
                int id = t + 512 * it;
                int c = id & 511;
                int row = c >> 3, q = c & 7;
                int off = row * 128 + ((q * 16) ^ ((row & 7) << 4));
                char* base = (id < 512) ? (char*)&Kl[buf ^ 1][0] : (char*)&Vl[buf ^ 1][0];
                *(bfx8*)(base + off) = sreg[it];
            }
        }
        __syncthreads();
        buf ^= 1;
    }

    // ---- output: O^T C-layout col q = lq, row d = (r&3)+8(r>>2)+4hi + db*32 ----
    const int b = bh >> 4, h = bh & 15;
    const float iv = __builtin_amdgcn_rcpf(lsum);
    unsigned short* orow = Ob + ((size_t)b * S_ + qr + lq) * D_ + h * 64;
#pragma unroll
    for (int db = 0; db < 2; ++db)
#pragma unroll
        for (int rq = 0; rq < 4; ++rq) {
            uint2 u;
            u.x = cvtpk(oacc[db][rq * 4 + 0] * iv, oacc[db][rq * 4 + 1] * iv);
            u.y = cvtpk(oacc[db][rq * 4 + 2] * iv, oacc[db][rq * 4 + 3] * iv);
            *(uint2*)&orow[db * 32 + rq * 8 + hi * 4] = u;
        }
}

// ---------------- out-proj GEMM: [8192,1024] x [1024,1024] + bias, f32 out ----------------
__launch_bounds__(256)
__global__ void k_gemm_proj(const unsigned short* __restrict__ A,
                            const unsigned short* __restrict__ Bt,
                            const float* __restrict__ bias,
                            float* __restrict__ out) {
    __shared__ unsigned short Al[128 * BK];
    __shared__ unsigned short Bl[128 * BK];
    const int wg = blockIdx.x;                 // 512 blocks: 8 n x 64 m
    const int lin = (wg & 7) * 64 + (wg >> 3);
    const int ny = lin >> 3, nx = lin & 7;
    const int m0 = ny * 128;
    const int n0 = nx * 128;
    const int t = threadIdx.x;
    const int w = t >> 6, l = t & 63;
    const int wr = w >> 1, wc = w & 1;
    const int lr = l & 15, lg = l >> 4;
    const int srow = l >> 2;
    const int scol = (l & 3) * 8;
    fx4 acc[4][4] = {};

    for (int k0 = 0; k0 < D_; k0 += BK) {
        __syncthreads();
#pragma unroll
        for (int j = 0; j < 2; ++j) {
            int rb = j * 64 + w * 16;
            gll16(&A [(size_t)(m0 + rb + srow) * D_ + k0 + scol], &Al[rb * BK]);
            gll16(&Bt[(size_t)(n0 + rb + srow) * D_ + k0 + scol], &Bl[rb * BK]);
        }
        __syncthreads();
        bfx8 af[4], bf[4];
#pragma unroll
        for (int i = 0; i < 4; ++i) af[i] = *(const bfx8*)&Al[(wr * 64 + i * 16 + lr) * BK + lg * 8];
#pragma unroll
        for (int i = 0; i < 4; ++i) bf[i] = *(const bfx8*)&Bl[(wc * 64 + i * 16 + lr) * BK + lg * 8];
#pragma unroll
        for (int mi = 0; mi < 4; ++mi)
#pragma unroll
            for (int ni = 0; ni < 4; ++ni)
                acc[mi][ni] = __builtin_amdgcn_mfma_f32_16x16x32_bf16(bf[ni], af[mi], acc[mi][ni], 0, 0, 0);
    }
#pragma unroll
    for (int ni = 0; ni < 4; ++ni) {
        const int nn = n0 + wc * 64 + ni * 16 + lg * 4;
        const float4 bv = *(const float4*)&bias[nn];
#pragma unroll
        for (int mi = 0; mi < 4; ++mi) {
            const int m = m0 + wr * 64 + mi * 16 + lr;
            fx4 v = acc[mi][ni];
            float4 o; o.x = v[0] + bv.x; o.y = v[1] + bv.y; o.z = v[2] + bv.z; o.w = v[3] + bv.w;
            *(float4*)&out[(size_t)m * D_ + nn] = o;
        }
    }
}

extern "C" void kernel_launch(void* const* d_in, const int* in_sizes, int n_in,
                              void* d_out, int out_size, void* d_ws, size_t ws_size,
                              hipStream_t stream) {
    const float* x     = (const float*)d_in[0];
    const float* w_qkv = (const float*)d_in[1];
    const float* b_qkv = (const float*)d_in[2];
    const float* w_out = (const float*)d_in[3];
    const float* b_out = (const float*)d_in[4];
    float* out = (float*)d_out;

    unsigned short* xb    = (unsigned short*)d_ws;          // 8192*1024 (reused as Vt after qkv)
    unsigned short* wqkvT = xb    + (size_t)MTOK * D_;      // 3072*1024
    unsigned short* woutT = wqkvT + (size_t)3 * D_ * D_;    // 1024*1024
    unsigned short* Qw    = woutT + (size_t)D_ * D_;        // 8192*1024
    unsigned short* Kw    = Qw    + (size_t)MTOK * D_;
    unsigned short* Vw    = Kw    + (size_t)MTOK * D_;
    unsigned short* attnb = Vw    + (size_t)MTOK * D_;
    unsigned short* Vt    = xb;   // alias: xb is dead after k_gemm_qkv

    k_conv_x<<<2048, 256, 0, stream>>>(x, xb, MTOK * D_ / 8);
    k_transpose_bf<<<(3 * D_ * (D_ / 8)) / 256, 256, 0, stream>>>(w_qkv, wqkvT, D_, 3 * D_);
    k_transpose_bf<<<(D_ * (D_ / 8)) / 256, 256, 0, stream>>>(w_out, woutT, D_, D_);
    k_gemm_qkv<<<1536, 256, 0, stream>>>(xb, wqkvT, b_qkv, Qw, Kw, Vw);
    k_transpose_v<<<2048, 256, 0, stream>>>(Vw, Vt);
    k_attn<<<512, 512, 0, stream>>>(Qw, Kw, Vt, attnb);
    k_gemm_proj<<<512, 256, 0, stream>>>(attnb, woutT, b_out, out);
}